// Round 17
// baseline (1027.590 us; speedup 1.0000x reference)
//
#include <hip/hip_runtime.h>
#include <hip/hip_bf16.h>
#include <math.h>

#define BB 4
#define SS 2048
#define EE 512
#define HH 8
#define DKK 64
#define LL 2
#define NBB 4
#define FFF 2048
#define CC 4
#define NBSE ((size_t)BB * SS * EE)

typedef __attribute__((ext_vector_type(8))) short bf16x8;
typedef __attribute__((ext_vector_type(4))) float f32x4;
using bf16 = __hip_bfloat16;

__device__ __forceinline__ float fast_exp2(float x) { return __builtin_amdgcn_exp2f(x); }

__device__ __forceinline__ void gload16(const bf16* g, bf16* l) {
    __builtin_amdgcn_global_load_lds((const __attribute__((address_space(1))) void*)g,
                                     (__attribute__((address_space(3))) void*)l, 16, 0, 0);
}
__device__ __forceinline__ unsigned short bf16bits(float f) {
    bf16 h = __float2bfloat16(f);
    return *(unsigned short*)&h;
}

// ---------------- embedding + positional encoding (f32 + bf16 copies) ----------------
__global__ __launch_bounds__(256) void embed_kernel(const int* __restrict__ tokens,
                                                    const float* __restrict__ emb,
                                                    float* __restrict__ x,
                                                    bf16* __restrict__ xb) {
    int i = blockIdx.x * blockDim.x + threadIdx.x;
    int total = BB * SS * EE / 2;
    if (i >= total) return;
    int pi  = i & (EE / 2 - 1);
    int row = i >> 8;
    int s   = row & (SS - 1);
    int tok = tokens[row];
    int e0  = pi * 2;
    const float kln = 9.210340371976184f / (float)EE;
    float arg = (float)s * expf(-(float)e0 * kln);
    float2 ev = *(const float2*)(emb + (size_t)tok * EE + e0);
    float2 o;
    o.x = ev.x + sinf(arg);
    o.y = ev.y + cosf(arg);
    *(float2*)(x + (size_t)row * EE + e0) = o;
    xb[(size_t)row * EE + e0]     = __float2bfloat16(o.x);
    xb[(size_t)row * EE + e0 + 1] = __float2bfloat16(o.y);
}

// ------- f32 [z][K][N] -> bf16 [z*zstride + (row_off+n)*K + k] transpose/cast -------
__global__ __launch_bounds__(256) void transpose_to_bf16(const float* __restrict__ in,
                                                         bf16* __restrict__ out,
                                                         int K, int N,
                                                         size_t zstride, int row_off) {
    const float* src = in + (size_t)blockIdx.z * K * N;
    bf16* dst = out + (size_t)blockIdx.z * zstride;
    int r0 = blockIdx.y * 64, c0 = blockIdx.x * 64;
    __shared__ float tl[64][65];
    int t = threadIdx.x;
    int lr = t >> 4, lc = (t & 15) * 4;
#pragma unroll
    for (int i = 0; i < 4; i++) {
        float4 v = *(const float4*)(src + (size_t)(r0 + lr + i * 16) * N + c0 + lc);
        tl[lr + i * 16][lc + 0] = v.x;
        tl[lr + i * 16][lc + 1] = v.y;
        tl[lr + i * 16][lc + 2] = v.z;
        tl[lr + i * 16][lc + 3] = v.w;
    }
    __syncthreads();
#pragma unroll
    for (int i = 0; i < 4; i++) {
        int n = lr + i * 16;
#pragma unroll
        for (int j = 0; j < 4; j++)
            dst[(size_t)(row_off + c0 + n) * K + r0 + lc + j] = __float2bfloat16(tl[lc + j][n]);
    }
}

// ---------------- bf16 MFMA GEMM (128x128 tile): C[M,N] = A[M,K] @ BT[N,K]^T ----------------
#define GF_RELU 1
#define GF_SCATTER3 2
#define GF_OUTBF16 4
__global__ __launch_bounds__(256) void gemm_bf16(const bf16* __restrict__ A,
                                                 const bf16* __restrict__ BT,
                                                 const float* __restrict__ bias,
                                                 void* __restrict__ C,
                                                 int M, int N, int K, int flags) {
    __shared__ __align__(16) bf16 Asm[128 * 32];
    __shared__ __align__(16) bf16 Bsm[128 * 32];
    int t = threadIdx.x;
    int l = t & 63, w = t >> 6;
    int nbx = gridDim.x;
    int lin = blockIdx.y * nbx + blockIdx.x;
    int cpx = (nbx * gridDim.y) >> 3;
    int swz = (lin & 7) * cpx + (lin >> 3);
    int bm = (swz / nbx) * 128, bn = (swz % nbx) * 128;
    int wr = (w >> 1) * 64, wc = (w & 1) * 64;
    int lr = l & 15, lg = l >> 4;
    int ca = w * 2;
    int sr = l >> 2, sk = (l & 3) * 8;
    const bf16* ga  = A  + (size_t)(bm + ca * 16 + sr) * K + sk;
    const bf16* ga2 = ga + (size_t)16 * K;
    const bf16* gb  = BT + (size_t)(bn + ca * 16 + sr) * K + sk;
    const bf16* gb2 = gb + (size_t)16 * K;

    f32x4 acc[4][4];
#pragma unroll
    for (int m = 0; m < 4; m++)
#pragma unroll
        for (int n = 0; n < 4; n++) acc[m][n] = (f32x4){0.f, 0.f, 0.f, 0.f};

    for (int k0 = 0; k0 < K; k0 += 32) {
        __syncthreads();
        gload16(ga + k0,  &Asm[ca * 512]);
        gload16(ga2 + k0, &Asm[ca * 512 + 512]);
        gload16(gb + k0,  &Bsm[ca * 512]);
        gload16(gb2 + k0, &Bsm[ca * 512 + 512]);
        __syncthreads();
        bf16x8 af[4], bfr[4];
#pragma unroll
        for (int m = 0; m < 4; m++)
            af[m] = *(const bf16x8*)&Asm[(wr + m * 16 + lr) * 32 + lg * 8];
#pragma unroll
        for (int n = 0; n < 4; n++)
            bfr[n] = *(const bf16x8*)&Bsm[(wc + n * 16 + lr) * 32 + lg * 8];
#pragma unroll
        for (int m = 0; m < 4; m++)
#pragma unroll
            for (int n = 0; n < 4; n++)
                acc[m][n] = __builtin_amdgcn_mfma_f32_16x16x32_bf16(af[m], bfr[n], acc[m][n], 0, 0, 0);
    }

#pragma unroll
    for (int m = 0; m < 4; m++) {
        int row = bm + wr + m * 16 + lg * 4;
#pragma unroll
        for (int n = 0; n < 4; n++) {
            int col = bn + wc + n * 16 + lr;
            float bv = bias ? bias[col] : 0.f;
#pragma unroll
            for (int r = 0; r < 4; r++) {
                float v = acc[m][n][r] + bv;
                if (flags & GF_RELU) v = fmaxf(v, 0.f);
                int rr = row + r;
                if (flags & GF_SCATTER3) {
                    int tsel = col >> 9;
                    int b = rr >> 11, s = rr & (SS - 1);
                    int h = (col >> 6) & 7, dk = col & 63;
                    ((bf16*)C)[tsel * NBSE + (((size_t)(b * HH + h) * SS + s) << 6) + dk] = __float2bfloat16(v);
                } else if (flags & GF_OUTBF16) {
                    ((bf16*)C)[(size_t)rr * N + col] = __float2bfloat16(v);
                } else {
                    ((float*)C)[(size_t)rr * N + col] = v;
                }
            }
        }
    }
}

// ------- bf16 MFMA GEMM (64x128 tile, for N=512 shapes: 2 blocks/CU instead of 1) -------
__global__ __launch_bounds__(256) void gemm_bf16_m64(const bf16* __restrict__ A,
                                                     const bf16* __restrict__ BT,
                                                     const float* __restrict__ bias,
                                                     void* __restrict__ C,
                                                     int M, int N, int K, int flags) {
    __shared__ __align__(16) bf16 Asm[64 * 32];
    __shared__ __align__(16) bf16 Bsm[128 * 32];
    int t = threadIdx.x;
    int l = t & 63, w = t >> 6;
    int nbx = gridDim.x;
    int lin = blockIdx.y * nbx + blockIdx.x;
    int cpx = (nbx * gridDim.y) >> 3;
    int swz = (lin & 7) * cpx + (lin >> 3);
    int bm = (swz / nbx) * 64, bn = (swz % nbx) * 128;
    int wr = (w >> 1) * 32, wc = (w & 1) * 64;
    int lr = l & 15, lg = l >> 4;
    int ca = w * 2;
    int sr = l >> 2, sk = (l & 3) * 8;
    const bf16* ga  = A  + (size_t)(bm + w * 16 + sr) * K + sk;
    const bf16* gb  = BT + (size_t)(bn + ca * 16 + sr) * K + sk;
    const bf16* gb2 = gb + (size_t)16 * K;

    f32x4 acc[2][4];
#pragma unroll
    for (int m = 0; m < 2; m++)
#pragma unroll
        for (int n = 0; n < 4; n++) acc[m][n] = (f32x4){0.f, 0.f, 0.f, 0.f};

    for (int k0 = 0; k0 < K; k0 += 32) {
        __syncthreads();
        gload16(ga + k0,  &Asm[w * 512]);
        gload16(gb + k0,  &Bsm[ca * 512]);
        gload16(gb2 + k0, &Bsm[ca * 512 + 512]);
        __syncthreads();
        bf16x8 af[2], bfr[4];
#pragma unroll
        for (int m = 0; m < 2; m++)
            af[m] = *(const bf16x8*)&Asm[(wr + m * 16 + lr) * 32 + lg * 8];
#pragma unroll
        for (int n = 0; n < 4; n++)
            bfr[n] = *(const bf16x8*)&Bsm[(wc + n * 16 + lr) * 32 + lg * 8];
#pragma unroll
        for (int m = 0; m < 2; m++)
#pragma unroll
            for (int n = 0; n < 4; n++)
                acc[m][n] = __builtin_amdgcn_mfma_f32_16x16x32_bf16(af[m], bfr[n], acc[m][n], 0, 0, 0);
    }

#pragma unroll
    for (int m = 0; m < 2; m++) {
        int row = bm + wr + m * 16 + lg * 4;
#pragma unroll
        for (int n = 0; n < 4; n++) {
            int col = bn + wc + n * 16 + lr;
            float bv = bias ? bias[col] : 0.f;
#pragma unroll
            for (int r = 0; r < 4; r++) {
                float v = acc[m][n][r] + bv;
                if (flags & GF_RELU) v = fmaxf(v, 0.f);
                int rr = row + r;
                if (flags & GF_OUTBF16) {
                    ((bf16*)C)[(size_t)rr * N + col] = __float2bfloat16(v);
                } else {
                    ((float*)C)[(size_t)rr * N + col] = v;
                }
            }
        }
    }
}

// ---------------- quantum per-head 2-layer linear, MFMA ----------------
__global__ __launch_bounds__(256) void quantum_mfma(bf16* __restrict__ qb, bf16* __restrict__ kb, bf16* __restrict__ vb,
                                                    bf16* __restrict__ vT,
                                                    const bf16* __restrict__ qwT, const bf16* __restrict__ kwT, const bf16* __restrict__ vwT,
                                                    const float* __restrict__ qbi, const float* __restrict__ kbi, const float* __restrict__ vbi) {
    __shared__ __align__(16) bf16 Hs[128 * 72];
    __shared__ __align__(16) bf16 W0s[64 * 72];
    __shared__ __align__(16) bf16 W1s[64 * 72];
    int z = blockIdx.z;
    bf16* hb       = z == 0 ? qb  : (z == 1 ? kb  : vb);
    const bf16* wT = z == 0 ? qwT : (z == 1 ? kwT : vwT);
    const float* bi = z == 0 ? qbi : (z == 1 ? kbi : vbi);
    int bh = blockIdx.y, h = bh & (HH - 1);
    int s0 = blockIdx.x * 128;
    int t = threadIdx.x, l = t & 63, w = t >> 6;
    int lr = l & 15, lg = l >> 4;
    bf16* base = hb + ((size_t)bh * SS + s0) * DKK;
    const bf16* w0p = wT + (size_t)h * 4096;
    const bf16* w1p = wT + (size_t)(HH + h) * 4096;
    {
        int r = t >> 1, dbase = (t & 1) * 32;
#pragma unroll
        for (int i = 0; i < 4; i++) {
            uint4 hv = *(const uint4*)(base + (size_t)r * 64 + dbase + i * 8);
            *(uint4*)&Hs[r * 72 + dbase + i * 8] = hv;
        }
        const bf16* wp = (t < 128) ? w0p : w1p;
        bf16* Ws = (t < 128) ? W0s : W1s;
        int tt = t & 127;
        int wr2 = tt >> 1, wd = (tt & 1) * 32;
#pragma unroll
        for (int i = 0; i < 4; i++) {
            uint4 wv = *(const uint4*)(wp + wr2 * 64 + wd + i * 8);
            *(uint4*)&Ws[wr2 * 72 + wd + i * 8] = wv;
        }
    }
    __syncthreads();
    f32x4 acc[2][4];
#pragma unroll
    for (int m = 0; m < 2; m++)
#pragma unroll
        for (int n = 0; n < 4; n++) acc[m][n] = (f32x4){0.f, 0.f, 0.f, 0.f};
    bf16x8 af[2][2];
#pragma unroll
    for (int m = 0; m < 2; m++)
#pragma unroll
        for (int ks = 0; ks < 2; ks++)
            af[m][ks] = *(const bf16x8*)&Hs[(w * 32 + m * 16 + lr) * 72 + ks * 32 + lg * 8];
#pragma unroll
    for (int n = 0; n < 4; n++)
#pragma unroll
        for (int ks = 0; ks < 2; ks++) {
            bf16x8 bfr = *(const bf16x8*)&W0s[(n * 16 + lr) * 72 + ks * 32 + lg * 8];
#pragma unroll
            for (int m = 0; m < 2; m++)
                acc[m][n] = __builtin_amdgcn_mfma_f32_16x16x32_bf16(af[m][ks], bfr, acc[m][n], 0, 0, 0);
        }
#pragma unroll
    for (int n = 0; n < 4; n++) {
        float b0 = bi[(size_t)h * 64 + n * 16 + lr];
#pragma unroll
        for (int m = 0; m < 2; m++)
#pragma unroll
            for (int r = 0; r < 4; r++)
                Hs[(w * 32 + m * 16 + lg * 4 + r) * 72 + n * 16 + lr] = __float2bfloat16(acc[m][n][r] + b0);
    }
    f32x4 acc2[2][4];
#pragma unroll
    for (int m = 0; m < 2; m++)
#pragma unroll
        for (int n = 0; n < 4; n++) acc2[m][n] = (f32x4){0.f, 0.f, 0.f, 0.f};
    bf16x8 af2[2][2];
#pragma unroll
    for (int m = 0; m < 2; m++)
#pragma unroll
        for (int ks = 0; ks < 2; ks++)
            af2[m][ks] = *(const bf16x8*)&Hs[(w * 32 + m * 16 + lr) * 72 + ks * 32 + lg * 8];
#pragma unroll
    for (int n = 0; n < 4; n++)
#pragma unroll
        for (int ks = 0; ks < 2; ks++) {
            bf16x8 bfr = *(const bf16x8*)&W1s[(n * 16 + lr) * 72 + ks * 32 + lg * 8];
#pragma unroll
            for (int m = 0; m < 2; m++)
                acc2[m][n] = __builtin_amdgcn_mfma_f32_16x16x32_bf16(af2[m][ks], bfr, acc2[m][n], 0, 0, 0);
        }
    if (z == 2) {
        __syncthreads();
        bf16* vt = Hs;
#pragma unroll
        for (int n = 0; n < 4; n++) {
            float b1 = bi[(size_t)(HH + h) * 64 + n * 16 + lr];
#pragma unroll
            for (int m = 0; m < 2; m++) {
                ushort4 pk;
                pk.x = bf16bits(acc2[m][n][0] + b1);
                pk.y = bf16bits(acc2[m][n][1] + b1);
                pk.z = bf16bits(acc2[m][n][2] + b1);
                pk.w = bf16bits(acc2[m][n][3] + b1);
                *(ushort4*)&vt[(n * 16 + lr) * 136 + w * 32 + m * 16 + lg * 4] = pk;
            }
        }
        __syncthreads();
        bf16* vbase = vT + (size_t)bh * DKK * SS + s0;
        int row = t >> 2, c0 = (t & 3) * 32;
#pragma unroll
        for (int i = 0; i < 4; i++)
            *(uint4*)(vbase + (size_t)row * SS + c0 + i * 8) = *(uint4*)&vt[row * 136 + c0 + i * 8];
    } else {
#pragma unroll
        for (int n = 0; n < 4; n++) {
            float b1 = bi[(size_t)(HH + h) * 64 + n * 16 + lr];
#pragma unroll
            for (int m = 0; m < 2; m++)
#pragma unroll
                for (int r = 0; r < 4; r++)
                    base[(size_t)(w * 32 + m * 16 + lg * 4 + r) * 64 + n * 16 + lr] = __float2bfloat16(acc2[m][n][r] + b1);
        }
    }
}

// ---- flash attention: 8 waves, 128 q/block, KVBLK=64, double-buffered LDS (1 barrier/iter),
//      defer-max + deferred l-sum ----
// q,k: [B,H,S,DK] bf16; vT: [B,H,DK,S] bf16; ao: [B,S,E] bf16
__global__ __launch_bounds__(512) __attribute__((amdgpu_waves_per_eu(6, 6)))
void attn_mfma(const bf16* __restrict__ q,
               const bf16* __restrict__ k,
               const bf16* __restrict__ vT,
               bf16* __restrict__ ao) {
    __shared__ __align__(16) bf16 Kbuf[2][64 * 72];
    __shared__ __align__(16) bf16 Vbuf[2][64 * 72];
    __shared__ __align__(16) bf16 Psm[8 * 16 * 68];
    int wg  = blockIdx.x;
    int nw  = (wg & 7) * 64 + (wg >> 3);   // XCD-bijective remap (512 %8==0)
    int bh  = nw >> 4;
    int q0  = (nw & 15) * 128;
    int b = bh >> 3, hh = bh & 7;
    int t = threadIdx.x, l = t & 63, w = t >> 6;
    int lr = l & 15, lg = l >> 4;
    bf16* Pw = &Psm[w * 16 * 68];

    bf16x8 qf[2];
#pragma unroll
    for (int ks = 0; ks < 2; ks++)
        qf[ks] = *(const bf16x8*)(q + ((size_t)bh * SS + q0 + w * 16 + lr) * DKK + ks * 32 + lg * 8);

    float m_run[4] = {-INFINITY, -INFINITY, -INFINITY, -INFINITY};
    float l_run[4] = {0.f, 0.f, 0.f, 0.f};
    f32x4 accO[4];
#pragma unroll
    for (int j = 0; j < 4; j++) accO[j] = (f32x4){0.f, 0.f, 0.f, 0.f};

    const bf16* kbase = k  + (size_t)bh * SS * DKK;
    const bf16* vbase = vT + (size_t)bh * DKK * SS;
    int srow = t >> 3, scol = (t & 7) * 8;

    uint4 kreg, vreg;
    // tile 0 -> regs -> buf0
    kreg = *(const uint4*)(kbase + (size_t)srow * DKK + scol);
    vreg = *(const uint4*)(vbase + (size_t)srow * SS + scol);
    *(uint4*)&Kbuf[0][srow * 72 + scol] = kreg;
    *(uint4*)&Vbuf[0][srow * 72 + scol] = vreg;
    // issue tile 1 loads (consumed at top of iter 0's staging for buf1)
    kreg = *(const uint4*)(kbase + (size_t)(64 + srow) * DKK + scol);
    vreg = *(const uint4*)(vbase + (size_t)srow * SS + 64 + scol);
    __syncthreads();   // buf0 visible

    const float SC = 0.180336879f;   // 0.125 * log2(e)
    int cur = 0;

    for (int kt = 0; kt < SS; kt += 64) {
        const bf16* Kc = Kbuf[cur];
        const bf16* Vc = Vbuf[cur];
        if (kt + 64 < SS) {
            // stage tile kt+64 into idle buffer (its last readers finished at prev barrier)
            *(uint4*)&Kbuf[cur ^ 1][srow * 72 + scol] = kreg;
            *(uint4*)&Vbuf[cur ^ 1][srow * 72 + scol] = vreg;
            if (kt + 128 < SS) {   // issue loads for tile kt+128; hide under compute
                kreg = *(const uint4*)(kbase + (size_t)(kt + 128 + srow) * DKK + scol);
                vreg = *(const uint4*)(vbase + (size_t)srow * SS + kt + 128 + scol);
            }
        }

        // S = Q K^T
        f32x4 s[4];
#pragma unroll
        for (int n = 0; n < 4; n++) s[n] = (f32x4){0.f, 0.f, 0.f, 0.f};
        __builtin_amdgcn_s_setprio(1);
#pragma unroll
        for (int n = 0; n < 4; n++)
#pragma unroll
            for (int ks = 0; ks < 2; ks++) {
                bf16x8 kf = *(const bf16x8*)&Kc[(n * 16 + lr) * 72 + ks * 32 + lg * 8];
                s[n] = __builtin_amdgcn_mfma_f32_16x16x32_bf16(qf[ks], kf, s[n], 0, 0, 0);
            }
        __builtin_amdgcn_s_setprio(0);

        // defer-max softmax (per-lane check; cross-lane reduce+rescale only when needed)
#pragma unroll
        for (int n = 0; n < 4; n++) s[n] *= SC;
        float mx[4];
#pragma unroll
        for (int r = 0; r < 4; r++)
            mx[r] = fmaxf(fmaxf(s[0][r], s[1][r]), fmaxf(s[2][r], s[3][r]));
        bool ok = true;
#pragma unroll
        for (int r = 0; r < 4; r++) ok = ok && (mx[r] <= m_run[r] + 8.f);
        if (!__all(ok)) {
#pragma unroll
            for (int r = 0; r < 4; r++) {
                float t2 = mx[r];
                t2 = fmaxf(t2, __shfl_xor(t2, 1, 16));
                t2 = fmaxf(t2, __shfl_xor(t2, 2, 16));
                t2 = fmaxf(t2, __shfl_xor(t2, 4, 16));
                t2 = fmaxf(t2, __shfl_xor(t2, 8, 16));
                float mn = fmaxf(m_run[r], t2);
                float fc = fast_exp2(m_run[r] - mn);
                m_run[r] = mn;
                l_run[r] *= fc;
#pragma unroll
                for (int j = 0; j < 4; j++) accO[j][r] *= fc;
            }
        }
#pragma unroll
        for (int n = 0; n < 4; n++)
#pragma unroll
            for (int r = 0; r < 4; r++) {
                float p = fast_exp2(s[n][r] - m_run[r]);
                l_run[r] += p;
                s[n][r] = p;
            }

        // P -> per-wave LDS region (same-wave producer/consumer)
#pragma unroll
        for (int n = 0; n < 4; n++)
#pragma unroll
            for (int r = 0; r < 4; r++)
                Pw[(lg * 4 + r) * 68 + n * 16 + lr] = __float2bfloat16(s[n][r]);

        // O += P V
        bf16x8 pa[2];
#pragma unroll
        for (int ks = 0; ks < 2; ks++)
            pa[ks] = *(const bf16x8*)&Pw[lr * 68 + ks * 32 + lg * 8];
        __builtin_amdgcn_s_setprio(1);
#pragma unroll
        for (int j = 0; j < 4; j++)
#pragma unroll
            for (int ks = 0; ks < 2; ks++) {
                bf16x8 vb8 = *(const bf16x8*)&Vc[(j * 16 + lr) * 72 + ks * 32 + lg * 8];
                accO[j] = __builtin_amdgcn_mfma_f32_16x16x32_bf16(pa[ks], vb8, accO[j], 0, 0, 0);
            }
        __builtin_amdgcn_s_setprio(0);

        if (kt + 64 < SS) {
            // publish idle-buffer writes; do NOT drain vmcnt (prefetch spans barrier)
            asm volatile("s_waitcnt lgkmcnt(0)" ::: "memory");
            __builtin_amdgcn_s_barrier();
        }
        cur ^= 1;
    }

    // final cross-lane reduction of per-lane l partials
    float inv[4];
#pragma unroll
    for (int r = 0; r < 4; r++) {
        float ls = l_run[r];
        ls += __shfl_xor(ls, 1, 16);
        ls += __shfl_xor(ls, 2, 16);
        ls += __shfl_xor(ls, 4, 16);
        ls += __shfl_xor(ls, 8, 16);
        inv[r] = 1.f / ls;
    }
#pragma unroll
    for (int j = 0; j < 4; j++)
#pragma unroll
        for (int r = 0; r < 4; r++) {
            int row = q0 + w * 16 + lg * 4 + r;
            ao[((size_t)(b * SS) + row) * EE + hh * 64 + j * 16 + lr] = __float2bfloat16(accO[j][r] * inv[r]);
        }
}

// ---------------- layernorm(x + res) in-place + bf16 copy ----------------
__global__ __launch_bounds__(256) void ln_kernel(float* __restrict__ x,
                                                 const float* __restrict__ res,
                                                 const float* __restrict__ g,
                                                 const float* __restrict__ beta,
                                                 bf16* __restrict__ xb) {
    int row = blockIdx.x;
    int t = threadIdx.x;
    float* xr = x + (size_t)row * EE;
    const float* rr = res + (size_t)row * EE;
    float v0 = xr[t] + rr[t];
    float v1 = xr[t + 256] + rr[t + 256];
    __shared__ float red[4];
    float s = v0 + v1;
#pragma unroll
    for (int m = 1; m < 64; m <<= 1) s += __shfl_xor(s, m, 64);
    if ((t & 63) == 0) red[t >> 6] = s;
    __syncthreads();
    s = red[0] + red[1] + red[2] + red[3];
    float mean = s * (1.f / EE);
    float d0 = v0 - mean, d1 = v1 - mean;
    float qv = d0 * d0 + d1 * d1;
    __syncthreads();
#pragma unroll
    for (int m = 1; m < 64; m <<= 1) qv += __shfl_xor(qv, m, 64);
    if ((t & 63) == 0) red[t >> 6] = qv;
    __syncthreads();
    qv = red[0] + red[1] + red[2] + red[3];
    float rs = rsqrtf(qv * (1.f / EE) + 1e-5f);
    float o0 = d0 * rs * g[t] + beta[t];
    float o1 = d1 * rs * g[t + 256] + beta[t + 256];
    xr[t] = o0;
    xr[t + 256] = o1;
    xb[(size_t)row * EE + t] = __float2bfloat16(o0);
    xb[(size_t)row * EE + t + 256] = __float2bfloat16(o1);
}

// ---------------- mean over S (two stage) + classifier ----------------
__global__ __launch_bounds__(256) void meanpart_kernel(const float* __restrict__ x,
                                                       float* __restrict__ part) {
    int b = blockIdx.y, c = blockIdx.x;
    int t = threadIdx.x;
    float s0 = 0.f, s1 = 0.f;
    for (int s = c * 32; s < c * 32 + 32; s++) {
        const float* row = x + ((size_t)b * SS + s) * EE;
        s0 += row[t];
        s1 += row[t + 256];
    }
    part[(size_t)(b * 64 + c) * EE + t] = s0;
    part[(size_t)(b * 64 + c) * EE + t + 256] = s1;
}

__global__ __launch_bounds__(256) void meancls_kernel(const float* __restrict__ part,
                                                      const float* __restrict__ cw,
                                                      const float* __restrict__ cb,
                                                      float* __restrict__ out) {
    int b = blockIdx.x;
    int t = threadIdx.x;
    __shared__ float xm[EE];
    float s0 = 0.f, s1 = 0.f;
    for (int i = 0; i < 64; i++) {
        s0 += part[(size_t)(b * 64 + i) * EE + t];
        s1 += part[(size_t)(b * 64 + i) * EE + t + 256];
    }
    xm[t] = s0 * (1.f / SS);
    xm[t + 256] = s1 * (1.f / SS);
    __syncthreads();
    if (t < CC) {
        float acc = cb[t];
        for (int e = 0; e < EE; e++) acc += xm[e] * cw[e * CC + t];
        out[b * CC + t] = acc;
    }
}

extern "C" void kernel_launch(void* const* d_in, const int* in_sizes, int n_in,
                              void* d_out, int out_size, void* d_ws, size_t ws_size,
                              hipStream_t stream) {
    (void)in_sizes; (void)n_in; (void)out_size; (void)ws_size;
    const int*   tokens = (const int*)d_in[0];
    const float* emb    = (const float*)d_in[1];
    const float* Wq     = (const float*)d_in[2];
    const float* Wk     = (const float*)d_in[3];
    const float* Wv     = (const float*)d_in[4];
    const float* Wo     = (const float*)d_in[5];
    const float* qh_w   = (const float*)d_in[6];
    const float* qh_b   = (const float*)d_in[7];
    const float* kh_w   = (const float*)d_in[8];
    const float* kh_b   = (const float*)d_in[9];
    const float* vh_w   = (const float*)d_in[10];
    const float* vh_b   = (const float*)d_in[11];
    const float* ln1_g  = (const float*)d_in[12];
    const float* ln1_b  = (const float*)d_in[13];
    const float* ln2_g  = (const float*)d_in[14];
    const float* ln2_b  = (const float*)d_in[15];
    const float* f_w1   = (const float*)d_in[16];
    const float* f_b1   = (const float*)d_in[17];
    const float* f_w2   = (const float*)d_in[18];
    const float* f_b2   = (const float*)d_in[19];
    const float* cls_w  = (const float*)d_in[20];
    const float* cls_b  = (const float*)d_in[21];

    const size_t nBSF = (size_t)BB * SS * FFF;
    float* x    = (float*)d_ws;
    float* t0   = x + NBSE;
    float* part = t0 + NBSE;
    bf16* xb    = (bf16*)(part + (size_t)BB * 64 * EE);
    bf16* qb    = xb + NBSE;
    bf16* kb    = qb + NBSE;
    bf16* vb    = kb + NBSE;
    bf16* vTb   = vb + NBSE;
    bf16* ao    = vTb + NBSE;
    bf16* ffnb  = ao + NBSE;
    bf16* WqkvT = ffnb + nBSF;
    bf16* WoT   = WqkvT + (size_t)NBB * 3 * EE * EE;
    bf16* fw1T  = WoT + (size_t)NBB * EE * EE;
    bf16* fw2T  = fw1T + (size_t)NBB * EE * FFF;
    bf16* qhT   = fw2T + (size_t)NBB * EE * FFF;
    bf16* khT   = qhT + (size_t)NBB * LL * HH * DKK * DKK;
    bf16* vhT   = khT + (size_t)NBB * LL * HH * DKK * DKK;

    const int M = BB * SS;   // 8192
    const size_t zQKV = (size_t)3 * EE * EE;

    transpose_to_bf16<<<dim3(EE / 64, EE / 64, NBB), 256, 0, stream>>>(Wq, WqkvT, EE, EE, zQKV, 0);
    transpose_to_bf16<<<dim3(EE / 64, EE / 64, NBB), 256, 0, stream>>>(Wk, WqkvT, EE, EE, zQKV, EE);
    transpose_to_bf16<<<dim3(EE / 64, EE / 64, NBB), 256, 0, stream>>>(Wv, WqkvT, EE, EE, zQKV, 2 * EE);
    transpose_to_bf16<<<dim3(EE / 64, EE / 64, NBB), 256, 0, stream>>>(Wo, WoT, EE, EE, (size_t)EE * EE, 0);
    transpose_to_bf16<<<dim3(FFF / 64, EE / 64, NBB), 256, 0, stream>>>(f_w1, fw1T, EE, FFF, (size_t)EE * FFF, 0);
    transpose_to_bf16<<<dim3(EE / 64, FFF / 64, NBB), 256, 0, stream>>>(f_w2, fw2T, FFF, EE, (size_t)EE * FFF, 0);
    transpose_to_bf16<<<dim3(1, 1, NBB * LL * HH), 256, 0, stream>>>(qh_w, qhT, DKK, DKK, (size_t)DKK * DKK, 0);
    transpose_to_bf16<<<dim3(1, 1, NBB * LL * HH), 256, 0, stream>>>(kh_w, khT, DKK, DKK, (size_t)DKK * DKK, 0);
    transpose_to_bf16<<<dim3(1, 1, NBB * LL * HH), 256, 0, stream>>>(vh_w, vhT, DKK, DKK, (size_t)DKK * DKK, 0);

    embed_kernel<<<(BB * SS * EE / 2 + 255) / 256, 256, 0, stream>>>(tokens, emb, x, xb);

    for (int blk = 0; blk < NBB; blk++) {
        dim3 gEE64(EE / 128, M / 64);    // (4,128) = 512 wgs
        dim3 gQKV(3 * EE / 128, M / 128);// (12,64)
        dim3 gFF(FFF / 128, M / 128);    // (16,64)
        const size_t wE = (size_t)blk * EE * EE;
        const size_t qwOff = (size_t)blk * LL * HH * DKK * DKK;
        const size_t qbOff = (size_t)blk * LL * HH * DKK;

        gemm_bf16<<<gQKV, 256, 0, stream>>>(xb, WqkvT + blk * zQKV, nullptr, qb, M, 3 * EE, EE, GF_SCATTER3);

        quantum_mfma<<<dim3(SS / 128, BB * HH, 3), 256, 0, stream>>>(
            qb, kb, vb, vTb, qhT + qwOff, khT + qwOff, vhT + qwOff,
            qh_b + qbOff, kh_b + qbOff, vh_b + qbOff);

        attn_mfma<<<dim3(512), 512, 0, stream>>>(qb, kb, vTb, ao);

        gemm_bf16_m64<<<gEE64, 256, 0, stream>>>(ao, WoT + wE, nullptr, t0, M, EE, EE, 0);
        ln_kernel<<<M, 256, 0, stream>>>(x, t0, ln1_g + blk * EE, ln1_b + blk * EE, xb);

        gemm_bf16<<<gFF, 256, 0, stream>>>(xb, fw1T + (size_t)blk * EE * FFF, f_b1 + blk * FFF, ffnb, M, FFF, EE, GF_RELU | GF_OUTBF16);
        gemm_bf16_m64<<<gEE64, 256, 0, stream>>>(ffnb, fw2T + (size_t)blk * EE * FFF, f_b2 + blk * EE, t0, M, EE, FFF, 0);
        ln_kernel<<<M, 256, 0, stream>>>(x, t0, ln2_g + blk * EE, ln2_b + blk * EE, xb);
    }

    meanpart_kernel<<<dim3(64, BB), 256, 0, stream>>>(x, part);
    meancls_kernel<<<BB, 256, 0, stream>>>(part, cls_w, cls_b, (float*)d_out);
}

// Round 18
// 1001.034 us; speedup vs baseline: 1.0265x; 1.0265x over previous
//
#include <hip/hip_runtime.h>
#include <hip/hip_bf16.h>
#include <math.h>

#define BB 4
#define SS 2048
#define EE 512
#define HH 8
#define DKK 64
#define LL 2
#define NBB 4
#define FFF 2048
#define CC 4
#define NBSE ((size_t)BB * SS * EE)

typedef __attribute__((ext_vector_type(8))) short bf16x8;
typedef __attribute__((ext_vector_type(4))) float f32x4;
using bf16 = __hip_bfloat16;

__device__ __forceinline__ float fast_exp2(float x) { return __builtin_amdgcn_exp2f(x); }

__device__ __forceinline__ void gload16(const bf16* g, bf16* l) {
    __builtin_amdgcn_global_load_lds((const __attribute__((address_space(1))) void*)g,
                                     (__attribute__((address_space(3))) void*)l, 16, 0, 0);
}
__device__ __forceinline__ unsigned short bf16bits(float f) {
    bf16 h = __float2bfloat16(f);
    return *(unsigned short*)&h;
}

// ---------------- embedding + positional encoding (f32 + bf16 copies) ----------------
__global__ __launch_bounds__(256) void embed_kernel(const int* __restrict__ tokens,
                                                    const float* __restrict__ emb,
                                                    float* __restrict__ x,
                                                    bf16* __restrict__ xb) {
    int i = blockIdx.x * blockDim.x + threadIdx.x;
    int total = BB * SS * EE / 2;
    if (i >= total) return;
    int pi  = i & (EE / 2 - 1);
    int row = i >> 8;
    int s   = row & (SS - 1);
    int tok = tokens[row];
    int e0  = pi * 2;
    const float kln = 9.210340371976184f / (float)EE;
    float arg = (float)s * expf(-(float)e0 * kln);
    float2 ev = *(const float2*)(emb + (size_t)tok * EE + e0);
    float2 o;
    o.x = ev.x + sinf(arg);
    o.y = ev.y + cosf(arg);
    *(float2*)(x + (size_t)row * EE + e0) = o;
    xb[(size_t)row * EE + e0]     = __float2bfloat16(o.x);
    xb[(size_t)row * EE + e0 + 1] = __float2bfloat16(o.y);
}

// ------- f32 [z][K][N] -> bf16 [z*zstride + (row_off+n)*K + k] transpose/cast -------
__global__ __launch_bounds__(256) void transpose_to_bf16(const float* __restrict__ in,
                                                         bf16* __restrict__ out,
                                                         int K, int N,
                                                         size_t zstride, int row_off) {
    const float* src = in + (size_t)blockIdx.z * K * N;
    bf16* dst = out + (size_t)blockIdx.z * zstride;
    int r0 = blockIdx.y * 64, c0 = blockIdx.x * 64;
    __shared__ float tl[64][65];
    int t = threadIdx.x;
    int lr = t >> 4, lc = (t & 15) * 4;
#pragma unroll
    for (int i = 0; i < 4; i++) {
        float4 v = *(const float4*)(src + (size_t)(r0 + lr + i * 16) * N + c0 + lc);
        tl[lr + i * 16][lc + 0] = v.x;
        tl[lr + i * 16][lc + 1] = v.y;
        tl[lr + i * 16][lc + 2] = v.z;
        tl[lr + i * 16][lc + 3] = v.w;
    }
    __syncthreads();
#pragma unroll
    for (int i = 0; i < 4; i++) {
        int n = lr + i * 16;
#pragma unroll
        for (int j = 0; j < 4; j++)
            dst[(size_t)(row_off + c0 + n) * K + r0 + lc + j] = __float2bfloat16(tl[lc + j][n]);
    }
}

// ---------------- bf16 MFMA GEMM (128x128 tile): C[M,N] = A[M,K] @ BT[N,K]^T ----------------
#define GF_RELU 1
#define GF_SCATTER3 2
#define GF_OUTBF16 4
__global__ __launch_bounds__(256) void gemm_bf16(const bf16* __restrict__ A,
                                                 const bf16* __restrict__ BT,
                                                 const float* __restrict__ bias,
                                                 void* __restrict__ C,
                                                 int M, int N, int K, int flags) {
    __shared__ __align__(16) bf16 Asm[128 * 32];
    __shared__ __align__(16) bf16 Bsm[128 * 32];
    int t = threadIdx.x;
    int l = t & 63, w = t >> 6;
    int nbx = gridDim.x;
    int lin = blockIdx.y * nbx + blockIdx.x;
    int cpx = (nbx * gridDim.y) >> 3;
    int swz = (lin & 7) * cpx + (lin >> 3);
    int bm = (swz / nbx) * 128, bn = (swz % nbx) * 128;
    int wr = (w >> 1) * 64, wc = (w & 1) * 64;
    int lr = l & 15, lg = l >> 4;
    int ca = w * 2;
    int sr = l >> 2, sk = (l & 3) * 8;
    const bf16* ga  = A  + (size_t)(bm + ca * 16 + sr) * K + sk;
    const bf16* ga2 = ga + (size_t)16 * K;
    const bf16* gb  = BT + (size_t)(bn + ca * 16 + sr) * K + sk;
    const bf16* gb2 = gb + (size_t)16 * K;

    f32x4 acc[4][4];
#pragma unroll
    for (int m = 0; m < 4; m++)
#pragma unroll
        for (int n = 0; n < 4; n++) acc[m][n] = (f32x4){0.f, 0.f, 0.f, 0.f};

    for (int k0 = 0; k0 < K; k0 += 32) {
        __syncthreads();
        gload16(ga + k0,  &Asm[ca * 512]);
        gload16(ga2 + k0, &Asm[ca * 512 + 512]);
        gload16(gb + k0,  &Bsm[ca * 512]);
        gload16(gb2 + k0, &Bsm[ca * 512 + 512]);
        __syncthreads();
        bf16x8 af[4], bfr[4];
#pragma unroll
        for (int m = 0; m < 4; m++)
            af[m] = *(const bf16x8*)&Asm[(wr + m * 16 + lr) * 32 + lg * 8];
#pragma unroll
        for (int n = 0; n < 4; n++)
            bfr[n] = *(const bf16x8*)&Bsm[(wc + n * 16 + lr) * 32 + lg * 8];
#pragma unroll
        for (int m = 0; m < 4; m++)
#pragma unroll
            for (int n = 0; n < 4; n++)
                acc[m][n] = __builtin_amdgcn_mfma_f32_16x16x32_bf16(af[m], bfr[n], acc[m][n], 0, 0, 0);
    }

#pragma unroll
    for (int m = 0; m < 4; m++) {
        int row = bm + wr + m * 16 + lg * 4;
#pragma unroll
        for (int n = 0; n < 4; n++) {
            int col = bn + wc + n * 16 + lr;
            float bv = bias ? bias[col] : 0.f;
#pragma unroll
            for (int r = 0; r < 4; r++) {
                float v = acc[m][n][r] + bv;
                if (flags & GF_RELU) v = fmaxf(v, 0.f);
                int rr = row + r;
                if (flags & GF_SCATTER3) {
                    int tsel = col >> 9;
                    int b = rr >> 11, s = rr & (SS - 1);
                    int h = (col >> 6) & 7, dk = col & 63;
                    ((bf16*)C)[tsel * NBSE + (((size_t)(b * HH + h) * SS + s) << 6) + dk] = __float2bfloat16(v);
                } else if (flags & GF_OUTBF16) {
                    ((bf16*)C)[(size_t)rr * N + col] = __float2bfloat16(v);
                } else {
                    ((float*)C)[(size_t)rr * N + col] = v;
                }
            }
        }
    }
}

// ------- bf16 MFMA GEMM (64x128 tile, for N=512 shapes: 2 blocks/CU instead of 1) -------
__global__ __launch_bounds__(256) void gemm_bf16_m64(const bf16* __restrict__ A,
                                                     const bf16* __restrict__ BT,
                                                     const float* __restrict__ bias,
                                                     void* __restrict__ C,
                                                     int M, int N, int K, int flags) {
    __shared__ __align__(16) bf16 Asm[64 * 32];
    __shared__ __align__(16) bf16 Bsm[128 * 32];
    int t = threadIdx.x;
    int l = t & 63, w = t >> 6;
    int nbx = gridDim.x;
    int lin = blockIdx.y * nbx + blockIdx.x;
    int cpx = (nbx * gridDim.y) >> 3;
    int swz = (lin & 7) * cpx + (lin >> 3);
    int bm = (swz / nbx) * 64, bn = (swz % nbx) * 128;
    int wr = (w >> 1) * 32, wc = (w & 1) * 64;
    int lr = l & 15, lg = l >> 4;
    int ca = w * 2;
    int sr = l >> 2, sk = (l & 3) * 8;
    const bf16* ga  = A  + (size_t)(bm + w * 16 + sr) * K + sk;
    const bf16* gb  = BT + (size_t)(bn + ca * 16 + sr) * K + sk;
    const bf16* gb2 = gb + (size_t)16 * K;

    f32x4 acc[2][4];
#pragma unroll
    for (int m = 0; m < 2; m++)
#pragma unroll
        for (int n = 0; n < 4; n++) acc[m][n] = (f32x4){0.f, 0.f, 0.f, 0.f};

    for (int k0 = 0; k0 < K; k0 += 32) {
        __syncthreads();
        gload16(ga + k0,  &Asm[w * 512]);
        gload16(gb + k0,  &Bsm[ca * 512]);
        gload16(gb2 + k0, &Bsm[ca * 512 + 512]);
        __syncthreads();
        bf16x8 af[2], bfr[4];
#pragma unroll
        for (int m = 0; m < 2; m++)
            af[m] = *(const bf16x8*)&Asm[(wr + m * 16 + lr) * 32 + lg * 8];
#pragma unroll
        for (int n = 0; n < 4; n++)
            bfr[n] = *(const bf16x8*)&Bsm[(wc + n * 16 + lr) * 32 + lg * 8];
#pragma unroll
        for (int m = 0; m < 2; m++)
#pragma unroll
            for (int n = 0; n < 4; n++)
                acc[m][n] = __builtin_amdgcn_mfma_f32_16x16x32_bf16(af[m], bfr[n], acc[m][n], 0, 0, 0);
    }

#pragma unroll
    for (int m = 0; m < 2; m++) {
        int row = bm + wr + m * 16 + lg * 4;
#pragma unroll
        for (int n = 0; n < 4; n++) {
            int col = bn + wc + n * 16 + lr;
            float bv = bias ? bias[col] : 0.f;
#pragma unroll
            for (int r = 0; r < 4; r++) {
                float v = acc[m][n][r] + bv;
                if (flags & GF_RELU) v = fmaxf(v, 0.f);
                int rr = row + r;
                if (flags & GF_OUTBF16) {
                    ((bf16*)C)[(size_t)rr * N + col] = __float2bfloat16(v);
                } else {
                    ((float*)C)[(size_t)rr * N + col] = v;
                }
            }
        }
    }
}

// ---------------- quantum per-head 2-layer linear, MFMA ----------------
__global__ __launch_bounds__(256) void quantum_mfma(bf16* __restrict__ qb, bf16* __restrict__ kb, bf16* __restrict__ vb,
                                                    bf16* __restrict__ vT,
                                                    const bf16* __restrict__ qwT, const bf16* __restrict__ kwT, const bf16* __restrict__ vwT,
                                                    const float* __restrict__ qbi, const float* __restrict__ kbi, const float* __restrict__ vbi) {
    __shared__ __align__(16) bf16 Hs[128 * 72];
    __shared__ __align__(16) bf16 W0s[64 * 72];
    __shared__ __align__(16) bf16 W1s[64 * 72];
    int z = blockIdx.z;
    bf16* hb       = z == 0 ? qb  : (z == 1 ? kb  : vb);
    const bf16* wT = z == 0 ? qwT : (z == 1 ? kwT : vwT);
    const float* bi = z == 0 ? qbi : (z == 1 ? kbi : vbi);
    int bh = blockIdx.y, h = bh & (HH - 1);
    int s0 = blockIdx.x * 128;
    int t = threadIdx.x, l = t & 63, w = t >> 6;
    int lr = l & 15, lg = l >> 4;
    bf16* base = hb + ((size_t)bh * SS + s0) * DKK;
    const bf16* w0p = wT + (size_t)h * 4096;
    const bf16* w1p = wT + (size_t)(HH + h) * 4096;
    {
        int r = t >> 1, dbase = (t & 1) * 32;
#pragma unroll
        for (int i = 0; i < 4; i++) {
            uint4 hv = *(const uint4*)(base + (size_t)r * 64 + dbase + i * 8);
            *(uint4*)&Hs[r * 72 + dbase + i * 8] = hv;
        }
        const bf16* wp = (t < 128) ? w0p : w1p;
        bf16* Ws = (t < 128) ? W0s : W1s;
        int tt = t & 127;
        int wr2 = tt >> 1, wd = (tt & 1) * 32;
#pragma unroll
        for (int i = 0; i < 4; i++) {
            uint4 wv = *(const uint4*)(wp + wr2 * 64 + wd + i * 8);
            *(uint4*)&Ws[wr2 * 72 + wd + i * 8] = wv;
        }
    }
    __syncthreads();
    f32x4 acc[2][4];
#pragma unroll
    for (int m = 0; m < 2; m++)
#pragma unroll
        for (int n = 0; n < 4; n++) acc[m][n] = (f32x4){0.f, 0.f, 0.f, 0.f};
    bf16x8 af[2][2];
#pragma unroll
    for (int m = 0; m < 2; m++)
#pragma unroll
        for (int ks = 0; ks < 2; ks++)
            af[m][ks] = *(const bf16x8*)&Hs[(w * 32 + m * 16 + lr) * 72 + ks * 32 + lg * 8];
#pragma unroll
    for (int n = 0; n < 4; n++)
#pragma unroll
        for (int ks = 0; ks < 2; ks++) {
            bf16x8 bfr = *(const bf16x8*)&W0s[(n * 16 + lr) * 72 + ks * 32 + lg * 8];
#pragma unroll
            for (int m = 0; m < 2; m++)
                acc[m][n] = __builtin_amdgcn_mfma_f32_16x16x32_bf16(af[m][ks], bfr, acc[m][n], 0, 0, 0);
        }
#pragma unroll
    for (int n = 0; n < 4; n++) {
        float b0 = bi[(size_t)h * 64 + n * 16 + lr];
#pragma unroll
        for (int m = 0; m < 2; m++)
#pragma unroll
            for (int r = 0; r < 4; r++)
                Hs[(w * 32 + m * 16 + lg * 4 + r) * 72 + n * 16 + lr] = __float2bfloat16(acc[m][n][r] + b0);
    }
    f32x4 acc2[2][4];
#pragma unroll
    for (int m = 0; m < 2; m++)
#pragma unroll
        for (int n = 0; n < 4; n++) acc2[m][n] = (f32x4){0.f, 0.f, 0.f, 0.f};
    bf16x8 af2[2][2];
#pragma unroll
    for (int m = 0; m < 2; m++)
#pragma unroll
        for (int ks = 0; ks < 2; ks++)
            af2[m][ks] = *(const bf16x8*)&Hs[(w * 32 + m * 16 + lr) * 72 + ks * 32 + lg * 8];
#pragma unroll
    for (int n = 0; n < 4; n++)
#pragma unroll
        for (int ks = 0; ks < 2; ks++) {
            bf16x8 bfr = *(const bf16x8*)&W1s[(n * 16 + lr) * 72 + ks * 32 + lg * 8];
#pragma unroll
            for (int m = 0; m < 2; m++)
                acc2[m][n] = __builtin_amdgcn_mfma_f32_16x16x32_bf16(af2[m][ks], bfr, acc2[m][n], 0, 0, 0);
        }
    if (z == 2) {
        __syncthreads();
        bf16* vt = Hs;
#pragma unroll
        for (int n = 0; n < 4; n++) {
            float b1 = bi[(size_t)(HH + h) * 64 + n * 16 + lr];
#pragma unroll
            for (int m = 0; m < 2; m++) {
                ushort4 pk;
                pk.x = bf16bits(acc2[m][n][0] + b1);
                pk.y = bf16bits(acc2[m][n][1] + b1);
                pk.z = bf16bits(acc2[m][n][2] + b1);
                pk.w = bf16bits(acc2[m][n][3] + b1);
                *(ushort4*)&vt[(n * 16 + lr) * 136 + w * 32 + m * 16 + lg * 4] = pk;
            }
        }
        __syncthreads();
        bf16* vbase = vT + (size_t)bh * DKK * SS + s0;
        int row = t >> 2, c0 = (t & 3) * 32;
#pragma unroll
        for (int i = 0; i < 4; i++)
            *(uint4*)(vbase + (size_t)row * SS + c0 + i * 8) = *(uint4*)&vt[row * 136 + c0 + i * 8];
    } else {
#pragma unroll
        for (int n = 0; n < 4; n++) {
            float b1 = bi[(size_t)(HH + h) * 64 + n * 16 + lr];
#pragma unroll
            for (int m = 0; m < 2; m++)
#pragma unroll
                for (int r = 0; r < 4; r++)
                    base[(size_t)(w * 32 + m * 16 + lg * 4 + r) * 64 + n * 16 + lr] = __float2bfloat16(acc2[m][n][r] + b1);
        }
    }
}

// ---- flash attention: 8 waves, 128 q/block, KVBLK=64, defer-max + deferred l-sum (R16) ----
// q,k: [B,H,S,DK] bf16; vT: [B,H,DK,S] bf16; ao: [B,S,E] bf16
__global__ __launch_bounds__(512) __attribute__((amdgpu_waves_per_eu(6, 6)))
void attn_mfma(const bf16* __restrict__ q,
               const bf16* __restrict__ k,
               const bf16* __restrict__ vT,
               bf16* __restrict__ ao) {
    __shared__ __align__(16) bf16 Ksm[64 * 72];
    __shared__ __align__(16) bf16 Vtm[64 * 72];
    __shared__ __align__(16) bf16 Psm[8 * 16 * 68];
    int wg  = blockIdx.x;
    int nw  = (wg & 7) * 64 + (wg >> 3);   // XCD-bijective remap (512 %8==0)
    int bh  = nw >> 4;
    int q0  = (nw & 15) * 128;
    int b = bh >> 3, hh = bh & 7;
    int t = threadIdx.x, l = t & 63, w = t >> 6;
    int lr = l & 15, lg = l >> 4;
    bf16* Pw = &Psm[w * 16 * 68];

    bf16x8 qf[2];
#pragma unroll
    for (int ks = 0; ks < 2; ks++)
        qf[ks] = *(const bf16x8*)(q + ((size_t)bh * SS + q0 + w * 16 + lr) * DKK + ks * 32 + lg * 8);

    float m_run[4] = {-INFINITY, -INFINITY, -INFINITY, -INFINITY};
    float l_run[4] = {0.f, 0.f, 0.f, 0.f};   // per-lane partial; reduced once after loop
    f32x4 accO[4];
#pragma unroll
    for (int j = 0; j < 4; j++) accO[j] = (f32x4){0.f, 0.f, 0.f, 0.f};

    const bf16* kbase = k  + (size_t)bh * SS * DKK;
    const bf16* vbase = vT + (size_t)bh * DKK * SS;
    int srow = t >> 3, scol = (t & 7) * 8;

    uint4 kreg, vreg;
    kreg = *(const uint4*)(kbase + (size_t)srow * DKK + scol);
    vreg = *(const uint4*)(vbase + (size_t)srow * SS + scol);

    const float SC = 0.180336879f;   // 0.125 * log2(e)

    for (int kt = 0; kt < SS; kt += 64) {
        __syncthreads();
        *(uint4*)&Ksm[srow * 72 + scol] = kreg;
        *(uint4*)&Vtm[srow * 72 + scol] = vreg;
        __syncthreads();
        if (kt + 64 < SS) {
            kreg = *(const uint4*)(kbase + (size_t)(kt + 64 + srow) * DKK + scol);
            vreg = *(const uint4*)(vbase + (size_t)srow * SS + kt + 64 + scol);
        }

        // S = Q K^T
        f32x4 s[4];
#pragma unroll
        for (int n = 0; n < 4; n++) s[n] = (f32x4){0.f, 0.f, 0.f, 0.f};
        __builtin_amdgcn_s_setprio(1);
#pragma unroll
        for (int n = 0; n < 4; n++)
#pragma unroll
            for (int ks = 0; ks < 2; ks++) {
                bf16x8 kf = *(const bf16x8*)&Ksm[(n * 16 + lr) * 72 + ks * 32 + lg * 8];
                s[n] = __builtin_amdgcn_mfma_f32_16x16x32_bf16(qf[ks], kf, s[n], 0, 0, 0);
            }
        __builtin_amdgcn_s_setprio(0);

        // defer-max softmax: per-lane max check; cross-lane reduce+rescale only when needed
#pragma unroll
        for (int n = 0; n < 4; n++) s[n] *= SC;
        float mx[4];
#pragma unroll
        for (int r = 0; r < 4; r++)
            mx[r] = fmaxf(fmaxf(s[0][r], s[1][r]), fmaxf(s[2][r], s[3][r]));
        bool ok = true;
#pragma unroll
        for (int r = 0; r < 4; r++) ok = ok && (mx[r] <= m_run[r] + 8.f);
        if (!__all(ok)) {
#pragma unroll
            for (int r = 0; r < 4; r++) {
                float t2 = mx[r];
                t2 = fmaxf(t2, __shfl_xor(t2, 1, 16));
                t2 = fmaxf(t2, __shfl_xor(t2, 2, 16));
                t2 = fmaxf(t2, __shfl_xor(t2, 4, 16));
                t2 = fmaxf(t2, __shfl_xor(t2, 8, 16));
                float mn = fmaxf(m_run[r], t2);
                float fc = fast_exp2(m_run[r] - mn);
                m_run[r] = mn;
                l_run[r] *= fc;
#pragma unroll
                for (int j = 0; j < 4; j++) accO[j][r] *= fc;
            }
        }
#pragma unroll
        for (int n = 0; n < 4; n++)
#pragma unroll
            for (int r = 0; r < 4; r++) {
                float p = fast_exp2(s[n][r] - m_run[r]);   // bounded by 2^8
                l_run[r] += p;
                s[n][r] = p;
            }

        // P -> per-wave LDS region (same-wave producer/consumer; no barrier needed)
#pragma unroll
        for (int n = 0; n < 4; n++)
#pragma unroll
            for (int r = 0; r < 4; r++)
                Pw[(lg * 4 + r) * 68 + n * 16 + lr] = __float2bfloat16(s[n][r]);

        // O += P V
        bf16x8 pa[2];
#pragma unroll
        for (int ks = 0; ks < 2; ks++)
            pa[ks] = *(const bf16x8*)&Pw[lr * 68 + ks * 32 + lg * 8];
        __builtin_amdgcn_s_setprio(1);
#pragma unroll
        for (int j = 0; j < 4; j++)
#pragma unroll
            for (int ks = 0; ks < 2; ks++) {
                bf16x8 vb8 = *(const bf16x8*)&Vtm[(j * 16 + lr) * 72 + ks * 32 + lg * 8];
                accO[j] = __builtin_amdgcn_mfma_f32_16x16x32_bf16(pa[ks], vb8, accO[j], 0, 0, 0);
            }
        __builtin_amdgcn_s_setprio(0);
    }

    // final cross-lane reduction of per-lane l partials
    float inv[4];
#pragma unroll
    for (int r = 0; r < 4; r++) {
        float ls = l_run[r];
        ls += __shfl_xor(ls, 1, 16);
        ls += __shfl_xor(ls, 2, 16);
        ls += __shfl_xor(ls, 4, 16);
        ls += __shfl_xor(ls, 8, 16);
        inv[r] = 1.f / ls;
    }
#pragma unroll
    for (int j = 0; j < 4; j++)
#pragma unroll
        for (int r = 0; r < 4; r++) {
            int row = q0 + w * 16 + lg * 4 + r;
            ao[((size_t)(b * SS) + row) * EE + hh * 64 + j * 16 + lr] = __float2bfloat16(accO[j][r] * inv[r]);
        }
}

// ---------------- layernorm(x + res) in-place + bf16 copy ----------------
__global__ __launch_bounds__(256) void ln_kernel(float* __restrict__ x,
                                                 const float* __restrict__ res,
                                                 const float* __restrict__ g,
                                                 const float* __restrict__ beta,
                                                 bf16* __restrict__ xb) {
    int row = blockIdx.x;
    int t = threadIdx.x;
    float* xr = x + (size_t)row * EE;
    const float* rr = res + (size_t)row * EE;
    float v0 = xr[t] + rr[t];
    float v1 = xr[t + 256] + rr[t + 256];
    __shared__ float red[4];
    float s = v0 + v1;
#pragma unroll
    for (int m = 1; m < 64; m <<= 1) s += __shfl_xor(s, m, 64);
    if ((t & 63) == 0) red[t >> 6] = s;
    __syncthreads();
    s = red[0] + red[1] + red[2] + red[3];
    float mean = s * (1.f / EE);
    float d0 = v0 - mean, d1 = v1 - mean;
    float qv = d0 * d0 + d1 * d1;
    __syncthreads();
#pragma unroll
    for (int m = 1; m < 64; m <<= 1) qv += __shfl_xor(qv, m, 64);
    if ((t & 63) == 0) red[t >> 6] = qv;
    __syncthreads();
    qv = red[0] + red[1] + red[2] + red[3];
    float rs = rsqrtf(qv * (1.f / EE) + 1e-5f);
    float o0 = d0 * rs * g[t] + beta[t];
    float o1 = d1 * rs * g[t + 256] + beta[t + 256];
    xr[t] = o0;
    xr[t + 256] = o1;
    xb[(size_t)row * EE + t] = __float2bfloat16(o0);
    xb[(size_t)row * EE + t + 256] = __float2bfloat16(o1);
}

// ---------------- mean over S (two stage) + classifier ----------------
__global__ __launch_bounds__(256) void meanpart_kernel(const float* __restrict__ x,
                                                       float* __restrict__ part) {
    int b = blockIdx.y, c = blockIdx.x;
    int t = threadIdx.x;
    float s0 = 0.f, s1 = 0.f;
    for (int s = c * 32; s < c * 32 + 32; s++) {
        const float* row = x + ((size_t)b * SS + s) * EE;
        s0 += row[t];
        s1 += row[t + 256];
    }
    part[(size_t)(b * 64 + c) * EE + t] = s0;
    part[(size_t)(b * 64 + c) * EE + t + 256] = s1;
}

__global__ __launch_bounds__(256) void meancls_kernel(const float* __restrict__ part,
                                                      const float* __restrict__ cw,
                                                      const float* __restrict__ cb,
                                                      float* __restrict__ out) {
    int b = blockIdx.x;
    int t = threadIdx.x;
    __shared__ float xm[EE];
    float s0 = 0.f, s1 = 0.f;
    for (int i = 0; i < 64; i++) {
        s0 += part[(size_t)(b * 64 + i) * EE + t];
        s1 += part[(size_t)(b * 64 + i) * EE + t + 256];
    }
    xm[t] = s0 * (1.f / SS);
    xm[t + 256] = s1 * (1.f / SS);
    __syncthreads();
    if (t < CC) {
        float acc = cb[t];
        for (int e = 0; e < EE; e++) acc += xm[e] * cw[e * CC + t];
        out[b * CC + t] = acc;
    }
}

extern "C" void kernel_launch(void* const* d_in, const int* in_sizes, int n_in,
                              void* d_out, int out_size, void* d_ws, size_t ws_size,
                              hipStream_t stream) {
    (void)in_sizes; (void)n_in; (void)out_size; (void)ws_size;
    const int*   tokens = (const int*)d_in[0];
    const float* emb    = (const float*)d_in[1];
    const float* Wq     = (const float*)d_in[2];
    const float* Wk     = (const float*)d_in[3];
    const float* Wv     = (const float*)d_in[4];
    const float* Wo     = (const float*)d_in[5];
    const float* qh_w   = (const float*)d_in[6];
    const float* qh_b   = (const float*)d_in[7];
    const float* kh_w   = (const float*)d_in[8];
    const float* kh_b   = (const float*)d_in[9];
    const float* vh_w   = (const float*)d_in[10];
    const float* vh_b   = (const float*)d_in[11];
    const float* ln1_g  = (const float*)d_in[12];
    const float* ln1_b  = (const float*)d_in[13];
    const float* ln2_g  = (const float*)d_in[14];
    const float* ln2_b  = (const float*)d_in[15];
    const float* f_w1   = (const float*)d_in[16];
    const float* f_b1   = (const float*)d_in[17];
    const float* f_w2   = (const float*)d_in[18];
    const float* f_b2   = (const float*)d_in[19];
    const float* cls_w  = (const float*)d_in[20];
    const float* cls_b  = (const float*)d_in[21];

    const size_t nBSF = (size_t)BB * SS * FFF;
    float* x    = (float*)d_ws;
    float* t0   = x + NBSE;
    float* part = t0 + NBSE;
    bf16* xb    = (bf16*)(part + (size_t)BB * 64 * EE);
    bf16* qb    = xb + NBSE;
    bf16* kb    = qb + NBSE;
    bf16* vb    = kb + NBSE;
    bf16* vTb   = vb + NBSE;
    bf16* ao    = vTb + NBSE;
    bf16* ffnb  = ao + NBSE;
    bf16* WqkvT = ffnb + nBSF;
    bf16* WoT   = WqkvT + (size_t)NBB * 3 * EE * EE;
    bf16* fw1T  = WoT + (size_t)NBB * EE * EE;
    bf16* fw2T  = fw1T + (size_t)NBB * EE * FFF;
    bf16* qhT   = fw2T + (size_t)NBB * EE * FFF;
    bf16* khT   = qhT + (size_t)NBB * LL * HH * DKK * DKK;
    bf16* vhT   = khT + (size_t)NBB * LL * HH * DKK * DKK;

    const int M = BB * SS;   // 8192
    const size_t zQKV = (size_t)3 * EE * EE;

    transpose_to_bf16<<<dim3(EE / 64, EE / 64, NBB), 256, 0, stream>>>(Wq, WqkvT, EE, EE, zQKV, 0);
    transpose_to_bf16<<<dim3(EE / 64, EE / 64, NBB), 256, 0, stream>>>(Wk, WqkvT, EE, EE, zQKV, EE);
    transpose_to_bf16<<<dim3(EE / 64, EE / 64, NBB), 256, 0, stream>>>(Wv, WqkvT, EE, EE, zQKV, 2 * EE);
    transpose_to_bf16<<<dim3(EE / 64, EE / 64, NBB), 256, 0, stream>>>(Wo, WoT, EE, EE, (size_t)EE * EE, 0);
    transpose_to_bf16<<<dim3(FFF / 64, EE / 64, NBB), 256, 0, stream>>>(f_w1, fw1T, EE, FFF, (size_t)EE * FFF, 0);
    transpose_to_bf16<<<dim3(EE / 64, FFF / 64, NBB), 256, 0, stream>>>(f_w2, fw2T, FFF, EE, (size_t)EE * FFF, 0);
    transpose_to_bf16<<<dim3(1, 1, NBB * LL * HH), 256, 0, stream>>>(qh_w, qhT, DKK, DKK, (size_t)DKK * DKK, 0);
    transpose_to_bf16<<<dim3(1, 1, NBB * LL * HH), 256, 0, stream>>>(kh_w, khT, DKK, DKK, (size_t)DKK * DKK, 0);
    transpose_to_bf16<<<dim3(1, 1, NBB * LL * HH), 256, 0, stream>>>(vh_w, vhT, DKK, DKK, (size_t)DKK * DKK, 0);

    embed_kernel<<<(BB * SS * EE / 2 + 255) / 256, 256, 0, stream>>>(tokens, emb, x, xb);

    for (int blk = 0; blk < NBB; blk++) {
        dim3 gEE64(EE / 128, M / 64);    // (4,128) = 512 wgs
        dim3 gQKV(3 * EE / 128, M / 128);// (12,64)
        dim3 gFF(FFF / 128, M / 128);    // (16,64)
        const size_t wE = (size_t)blk * EE * EE;
        const size_t qwOff = (size_t)blk * LL * HH * DKK * DKK;
        const size_t qbOff = (size_t)blk * LL * HH * DKK;

        gemm_bf16<<<gQKV, 256, 0, stream>>>(xb, WqkvT + blk * zQKV, nullptr, qb, M, 3 * EE, EE, GF_SCATTER3);

        quantum_mfma<<<dim3(SS / 128, BB * HH, 3), 256, 0, stream>>>(
            qb, kb, vb, vTb, qhT + qwOff, khT + qwOff, vhT + qwOff,
            qh_b + qbOff, kh_b + qbOff, vh_b + qbOff);

        attn_mfma<<<dim3(512), 512, 0, stream>>>(qb, kb, vTb, ao);

        gemm_bf16_m64<<<gEE64, 256, 0, stream>>>(ao, WoT + wE, nullptr, t0, M, EE, EE, 0);
        ln_kernel<<<M, 256, 0, stream>>>(x, t0, ln1_g + blk * EE, ln1_b + blk * EE, xb);

        gemm_bf16<<<gFF, 256, 0, stream>>>(xb, fw1T + (size_t)blk * EE * FFF, f_b1 + blk * FFF, ffnb, M, FFF, EE, GF_RELU | GF_OUTBF16);
        gemm_bf16_m64<<<gEE64, 256, 0, stream>>>(ffnb, fw2T + (size_t)blk * EE * FFF, f_b2 + blk * EE, t0, M, EE, FFF, 0);
        ln_kernel<<<M, 256, 0, stream>>>(x, t0, ln2_g + blk * EE, ln2_b + blk * EE, xb);
    }

    meanpart_kernel<<<dim3(64, BB), 256, 0, stream>>>(x, part);
    meancls_kernel<<<BB, 256, 0, stream>>>(part, cls_w, cls_b, (float*)d_out);
}

// Round 19
// 986.354 us; speedup vs baseline: 1.0418x; 1.0149x over previous
//
#include <hip/hip_runtime.h>
#include <hip/hip_bf16.h>
#include <math.h>

#define BB 4
#define SS 2048
#define EE 512
#define HH 8
#define DKK 64
#define LL 2
#define NBB 4
#define FFF 2048
#define CC 4
#define NBSE ((size_t)BB * SS * EE)

typedef __attribute__((ext_vector_type(8))) short bf16x8;
typedef __attribute__((ext_vector_type(4))) float f32x4;
using bf16 = __hip_bfloat16;

__device__ __forceinline__ float fast_exp2(float x) { return __builtin_amdgcn_exp2f(x); }

__device__ __forceinline__ void gload16(const bf16* g, bf16* l) {
    __builtin_amdgcn_global_load_lds((const __attribute__((address_space(1))) void*)g,
                                     (__attribute__((address_space(3))) void*)l, 16, 0, 0);
}
__device__ __forceinline__ unsigned short bf16bits(float f) {
    bf16 h = __float2bfloat16(f);
    return *(unsigned short*)&h;
}

// ---------------- embedding + positional encoding (f32 + bf16 copies) ----------------
__global__ __launch_bounds__(256) void embed_kernel(const int* __restrict__ tokens,
                                                    const float* __restrict__ emb,
                                                    float* __restrict__ x,
                                                    bf16* __restrict__ xb) {
    int i = blockIdx.x * blockDim.x + threadIdx.x;
    int total = BB * SS * EE / 2;
    if (i >= total) return;
    int pi  = i & (EE / 2 - 1);
    int row = i >> 8;
    int s   = row & (SS - 1);
    int tok = tokens[row];
    int e0  = pi * 2;
    const float kln = 9.210340371976184f / (float)EE;
    float arg = (float)s * expf(-(float)e0 * kln);
    float2 ev = *(const float2*)(emb + (size_t)tok * EE + e0);
    float2 o;
    o.x = ev.x + sinf(arg);
    o.y = ev.y + cosf(arg);
    *(float2*)(x + (size_t)row * EE + e0) = o;
    xb[(size_t)row * EE + e0]     = __float2bfloat16(o.x);
    xb[(size_t)row * EE + e0 + 1] = __float2bfloat16(o.y);
}

// ------- f32 [z][K][N] -> bf16 [z*zstride + (row_off+n)*K + k] transpose/cast -------
__global__ __launch_bounds__(256) void transpose_to_bf16(const float* __restrict__ in,
                                                         bf16* __restrict__ out,
                                                         int K, int N,
                                                         size_t zstride, int row_off) {
    const float* src = in + (size_t)blockIdx.z * K * N;
    bf16* dst = out + (size_t)blockIdx.z * zstride;
    int r0 = blockIdx.y * 64, c0 = blockIdx.x * 64;
    __shared__ float tl[64][65];
    int t = threadIdx.x;
    int lr = t >> 4, lc = (t & 15) * 4;
#pragma unroll
    for (int i = 0; i < 4; i++) {
        float4 v = *(const float4*)(src + (size_t)(r0 + lr + i * 16) * N + c0 + lc);
        tl[lr + i * 16][lc + 0] = v.x;
        tl[lr + i * 16][lc + 1] = v.y;
        tl[lr + i * 16][lc + 2] = v.z;
        tl[lr + i * 16][lc + 3] = v.w;
    }
    __syncthreads();
#pragma unroll
    for (int i = 0; i < 4; i++) {
        int n = lr + i * 16;
#pragma unroll
        for (int j = 0; j < 4; j++)
            dst[(size_t)(row_off + c0 + n) * K + r0 + lc + j] = __float2bfloat16(tl[lc + j][n]);
    }
}

// ---------------- bf16 MFMA GEMM (128x128 tile): C[M,N] = A[M,K] @ BT[N,K]^T ----------------
#define GF_RELU 1
#define GF_SCATTER3 2
#define GF_OUTBF16 4
__global__ __launch_bounds__(256) void gemm_bf16(const bf16* __restrict__ A,
                                                 const bf16* __restrict__ BT,
                                                 const float* __restrict__ bias,
                                                 void* __restrict__ C,
                                                 int M, int N, int K, int flags) {
    __shared__ __align__(16) bf16 Asm[128 * 32];
    __shared__ __align__(16) bf16 Bsm[128 * 32];
    int t = threadIdx.x;
    int l = t & 63, w = t >> 6;
    int nbx = gridDim.x;
    int lin = blockIdx.y * nbx + blockIdx.x;
    int cpx = (nbx * gridDim.y) >> 3;
    int swz = (lin & 7) * cpx + (lin >> 3);
    int bm = (swz / nbx) * 128, bn = (swz % nbx) * 128;
    int wr = (w >> 1) * 64, wc = (w & 1) * 64;
    int lr = l & 15, lg = l >> 4;
    int ca = w * 2;
    int sr = l >> 2, sk = (l & 3) * 8;
    const bf16* ga  = A  + (size_t)(bm + ca * 16 + sr) * K + sk;
    const bf16* ga2 = ga + (size_t)16 * K;
    const bf16* gb  = BT + (size_t)(bn + ca * 16 + sr) * K + sk;
    const bf16* gb2 = gb + (size_t)16 * K;

    f32x4 acc[4][4];
#pragma unroll
    for (int m = 0; m < 4; m++)
#pragma unroll
        for (int n = 0; n < 4; n++) acc[m][n] = (f32x4){0.f, 0.f, 0.f, 0.f};

    for (int k0 = 0; k0 < K; k0 += 32) {
        __syncthreads();
        gload16(ga + k0,  &Asm[ca * 512]);
        gload16(ga2 + k0, &Asm[ca * 512 + 512]);
        gload16(gb + k0,  &Bsm[ca * 512]);
        gload16(gb2 + k0, &Bsm[ca * 512 + 512]);
        __syncthreads();
        bf16x8 af[4], bfr[4];
#pragma unroll
        for (int m = 0; m < 4; m++)
            af[m] = *(const bf16x8*)&Asm[(wr + m * 16 + lr) * 32 + lg * 8];
#pragma unroll
        for (int n = 0; n < 4; n++)
            bfr[n] = *(const bf16x8*)&Bsm[(wc + n * 16 + lr) * 32 + lg * 8];
#pragma unroll
        for (int m = 0; m < 4; m++)
#pragma unroll
            for (int n = 0; n < 4; n++)
                acc[m][n] = __builtin_amdgcn_mfma_f32_16x16x32_bf16(af[m], bfr[n], acc[m][n], 0, 0, 0);
    }

#pragma unroll
    for (int m = 0; m < 4; m++) {
        int row = bm + wr + m * 16 + lg * 4;
#pragma unroll
        for (int n = 0; n < 4; n++) {
            int col = bn + wc + n * 16 + lr;
            float bv = bias ? bias[col] : 0.f;
#pragma unroll
            for (int r = 0; r < 4; r++) {
                float v = acc[m][n][r] + bv;
                if (flags & GF_RELU) v = fmaxf(v, 0.f);
                int rr = row + r;
                if (flags & GF_SCATTER3) {
                    int tsel = col >> 9;
                    int b = rr >> 11, s = rr & (SS - 1);
                    int h = (col >> 6) & 7, dk = col & 63;
                    ((bf16*)C)[tsel * NBSE + (((size_t)(b * HH + h) * SS + s) << 6) + dk] = __float2bfloat16(v);
                } else if (flags & GF_OUTBF16) {
                    ((bf16*)C)[(size_t)rr * N + col] = __float2bfloat16(v);
                } else {
                    ((float*)C)[(size_t)rr * N + col] = v;
                }
            }
        }
    }
}

// ------- bf16 MFMA GEMM (64x128 tile, for N=512 shapes: 2 blocks/CU instead of 1) -------
__global__ __launch_bounds__(256) void gemm_bf16_m64(const bf16* __restrict__ A,
                                                     const bf16* __restrict__ BT,
                                                     const float* __restrict__ bias,
                                                     void* __restrict__ C,
                                                     int M, int N, int K, int flags) {
    __shared__ __align__(16) bf16 Asm[64 * 32];
    __shared__ __align__(16) bf16 Bsm[128 * 32];
    int t = threadIdx.x;
    int l = t & 63, w = t >> 6;
    int nbx = gridDim.x;
    int lin = blockIdx.y * nbx + blockIdx.x;
    int cpx = (nbx * gridDim.y) >> 3;
    int swz = (lin & 7) * cpx + (lin >> 3);
    int bm = (swz / nbx) * 64, bn = (swz % nbx) * 128;
    int wr = (w >> 1) * 32, wc = (w & 1) * 64;
    int lr = l & 15, lg = l >> 4;
    int ca = w * 2;
    int sr = l >> 2, sk = (l & 3) * 8;
    const bf16* ga  = A  + (size_t)(bm + w * 16 + sr) * K + sk;
    const bf16* gb  = BT + (size_t)(bn + ca * 16 + sr) * K + sk;
    const bf16* gb2 = gb + (size_t)16 * K;

    f32x4 acc[2][4];
#pragma unroll
    for (int m = 0; m < 2; m++)
#pragma unroll
        for (int n = 0; n < 4; n++) acc[m][n] = (f32x4){0.f, 0.f, 0.f, 0.f};

    for (int k0 = 0; k0 < K; k0 += 32) {
        __syncthreads();
        gload16(ga + k0,  &Asm[w * 512]);
        gload16(gb + k0,  &Bsm[ca * 512]);
        gload16(gb2 + k0, &Bsm[ca * 512 + 512]);
        __syncthreads();
        bf16x8 af[2], bfr[4];
#pragma unroll
        for (int m = 0; m < 2; m++)
            af[m] = *(const bf16x8*)&Asm[(wr + m * 16 + lr) * 32 + lg * 8];
#pragma unroll
        for (int n = 0; n < 4; n++)
            bfr[n] = *(const bf16x8*)&Bsm[(wc + n * 16 + lr) * 32 + lg * 8];
#pragma unroll
        for (int m = 0; m < 2; m++)
#pragma unroll
            for (int n = 0; n < 4; n++)
                acc[m][n] = __builtin_amdgcn_mfma_f32_16x16x32_bf16(af[m], bfr[n], acc[m][n], 0, 0, 0);
    }

#pragma unroll
    for (int m = 0; m < 2; m++) {
        int row = bm + wr + m * 16 + lg * 4;
#pragma unroll
        for (int n = 0; n < 4; n++) {
            int col = bn + wc + n * 16 + lr;
            float bv = bias ? bias[col] : 0.f;
#pragma unroll
            for (int r = 0; r < 4; r++) {
                float v = acc[m][n][r] + bv;
                if (flags & GF_RELU) v = fmaxf(v, 0.f);
                int rr = row + r;
                if (flags & GF_OUTBF16) {
                    ((bf16*)C)[(size_t)rr * N + col] = __float2bfloat16(v);
                } else {
                    ((float*)C)[(size_t)rr * N + col] = v;
                }
            }
        }
    }
}

// ---------------- quantum per-head 2-layer linear, MFMA ----------------
__global__ __launch_bounds__(256) void quantum_mfma(bf16* __restrict__ qb, bf16* __restrict__ kb, bf16* __restrict__ vb,
                                                    bf16* __restrict__ vT,
                                                    const bf16* __restrict__ qwT, const bf16* __restrict__ kwT, const bf16* __restrict__ vwT,
                                                    const float* __restrict__ qbi, const float* __restrict__ kbi, const float* __restrict__ vbi) {
    __shared__ __align__(16) bf16 Hs[128 * 72];
    __shared__ __align__(16) bf16 W0s[64 * 72];
    __shared__ __align__(16) bf16 W1s[64 * 72];
    int z = blockIdx.z;
    bf16* hb       = z == 0 ? qb  : (z == 1 ? kb  : vb);
    const bf16* wT = z == 0 ? qwT : (z == 1 ? kwT : vwT);
    const float* bi = z == 0 ? qbi : (z == 1 ? kbi : vbi);
    int bh = blockIdx.y, h = bh & (HH - 1);
    int s0 = blockIdx.x * 128;
    int t = threadIdx.x, l = t & 63, w = t >> 6;
    int lr = l & 15, lg = l >> 4;
    bf16* base = hb + ((size_t)bh * SS + s0) * DKK;
    const bf16* w0p = wT + (size_t)h * 4096;
    const bf16* w1p = wT + (size_t)(HH + h) * 4096;
    {
        int r = t >> 1, dbase = (t & 1) * 32;
#pragma unroll
        for (int i = 0; i < 4; i++) {
            uint4 hv = *(const uint4*)(base + (size_t)r * 64 + dbase + i * 8);
            *(uint4*)&Hs[r * 72 + dbase + i * 8] = hv;
        }
        const bf16* wp = (t < 128) ? w0p : w1p;
        bf16* Ws = (t < 128) ? W0s : W1s;
        int tt = t & 127;
        int wr2 = tt >> 1, wd = (tt & 1) * 32;
#pragma unroll
        for (int i = 0; i < 4; i++) {
            uint4 wv = *(const uint4*)(wp + wr2 * 64 + wd + i * 8);
            *(uint4*)&Ws[wr2 * 72 + wd + i * 8] = wv;
        }
    }
    __syncthreads();
    f32x4 acc[2][4];
#pragma unroll
    for (int m = 0; m < 2; m++)
#pragma unroll
        for (int n = 0; n < 4; n++) acc[m][n] = (f32x4){0.f, 0.f, 0.f, 0.f};
    bf16x8 af[2][2];
#pragma unroll
    for (int m = 0; m < 2; m++)
#pragma unroll
        for (int ks = 0; ks < 2; ks++)
            af[m][ks] = *(const bf16x8*)&Hs[(w * 32 + m * 16 + lr) * 72 + ks * 32 + lg * 8];
#pragma unroll
    for (int n = 0; n < 4; n++)
#pragma unroll
        for (int ks = 0; ks < 2; ks++) {
            bf16x8 bfr = *(const bf16x8*)&W0s[(n * 16 + lr) * 72 + ks * 32 + lg * 8];
#pragma unroll
            for (int m = 0; m < 2; m++)
                acc[m][n] = __builtin_amdgcn_mfma_f32_16x16x32_bf16(af[m][ks], bfr, acc[m][n], 0, 0, 0);
        }
#pragma unroll
    for (int n = 0; n < 4; n++) {
        float b0 = bi[(size_t)h * 64 + n * 16 + lr];
#pragma unroll
        for (int m = 0; m < 2; m++)
#pragma unroll
            for (int r = 0; r < 4; r++)
                Hs[(w * 32 + m * 16 + lg * 4 + r) * 72 + n * 16 + lr] = __float2bfloat16(acc[m][n][r] + b0);
    }
    f32x4 acc2[2][4];
#pragma unroll
    for (int m = 0; m < 2; m++)
#pragma unroll
        for (int n = 0; n < 4; n++) acc2[m][n] = (f32x4){0.f, 0.f, 0.f, 0.f};
    bf16x8 af2[2][2];
#pragma unroll
    for (int m = 0; m < 2; m++)
#pragma unroll
        for (int ks = 0; ks < 2; ks++)
            af2[m][ks] = *(const bf16x8*)&Hs[(w * 32 + m * 16 + lr) * 72 + ks * 32 + lg * 8];
#pragma unroll
    for (int n = 0; n < 4; n++)
#pragma unroll
        for (int ks = 0; ks < 2; ks++) {
            bf16x8 bfr = *(const bf16x8*)&W1s[(n * 16 + lr) * 72 + ks * 32 + lg * 8];
#pragma unroll
            for (int m = 0; m < 2; m++)
                acc2[m][n] = __builtin_amdgcn_mfma_f32_16x16x32_bf16(af2[m][ks], bfr, acc2[m][n], 0, 0, 0);
        }
    if (z == 2) {
        __syncthreads();
        bf16* vt = Hs;
#pragma unroll
        for (int n = 0; n < 4; n++) {
            float b1 = bi[(size_t)(HH + h) * 64 + n * 16 + lr];
#pragma unroll
            for (int m = 0; m < 2; m++) {
                ushort4 pk;
                pk.x = bf16bits(acc2[m][n][0] + b1);
                pk.y = bf16bits(acc2[m][n][1] + b1);
                pk.z = bf16bits(acc2[m][n][2] + b1);
                pk.w = bf16bits(acc2[m][n][3] + b1);
                *(ushort4*)&vt[(n * 16 + lr) * 136 + w * 32 + m * 16 + lg * 4] = pk;
            }
        }
        __syncthreads();
        bf16* vbase = vT + (size_t)bh * DKK * SS + s0;
        int row = t >> 2, c0 = (t & 3) * 32;
#pragma unroll
        for (int i = 0; i < 4; i++)
            *(uint4*)(vbase + (size_t)row * SS + c0 + i * 8) = *(uint4*)&vt[row * 136 + c0 + i * 8];
    } else {
#pragma unroll
        for (int n = 0; n < 4; n++) {
            float b1 = bi[(size_t)(HH + h) * 64 + n * 16 + lr];
#pragma unroll
            for (int m = 0; m < 2; m++)
#pragma unroll
                for (int r = 0; r < 4; r++)
                    base[(size_t)(w * 32 + m * 16 + lg * 4 + r) * 64 + n * 16 + lr] = __float2bfloat16(acc2[m][n][r] + b1);
        }
    }
}

// ---- flash attention: 8 waves, 128 q/block, KVBLK=64, defer-max + deferred l-sum (R16) ----
// q,k: [B,H,S,DK] bf16; vT: [B,H,DK,S] bf16; ao: [B,S,E] bf16
__global__ __launch_bounds__(512) __attribute__((amdgpu_waves_per_eu(6, 6)))
void attn_mfma(const bf16* __restrict__ q,
               const bf16* __restrict__ k,
               const bf16* __restrict__ vT,
               bf16* __restrict__ ao) {
    __shared__ __align__(16) bf16 Ksm[64 * 72];
    __shared__ __align__(16) bf16 Vtm[64 * 72];
    __shared__ __align__(16) bf16 Psm[8 * 16 * 68];
    int wg  = blockIdx.x;
    int nw  = (wg & 7) * 64 + (wg >> 3);   // XCD-bijective remap (512 %8==0)
    int bh  = nw >> 4;
    int q0  = (nw & 15) * 128;
    int b = bh >> 3, hh = bh & 7;
    int t = threadIdx.x, l = t & 63, w = t >> 6;
    int lr = l & 15, lg = l >> 4;
    bf16* Pw = &Psm[w * 16 * 68];

    bf16x8 qf[2];
#pragma unroll
    for (int ks = 0; ks < 2; ks++)
        qf[ks] = *(const bf16x8*)(q + ((size_t)bh * SS + q0 + w * 16 + lr) * DKK + ks * 32 + lg * 8);

    float m_run[4] = {-INFINITY, -INFINITY, -INFINITY, -INFINITY};
    float l_run[4] = {0.f, 0.f, 0.f, 0.f};
    f32x4 accO[4];
#pragma unroll
    for (int j = 0; j < 4; j++) accO[j] = (f32x4){0.f, 0.f, 0.f, 0.f};

    const bf16* kbase = k  + (size_t)bh * SS * DKK;
    const bf16* vbase = vT + (size_t)bh * DKK * SS;
    int srow = t >> 3, scol = (t & 7) * 8;

    uint4 kreg, vreg;
    kreg = *(const uint4*)(kbase + (size_t)srow * DKK + scol);
    vreg = *(const uint4*)(vbase + (size_t)srow * SS + scol);

    const float SC = 0.180336879f;   // 0.125 * log2(e)

    for (int kt = 0; kt < SS; kt += 64) {
        __syncthreads();
        *(uint4*)&Ksm[srow * 72 + scol] = kreg;
        *(uint4*)&Vtm[srow * 72 + scol] = vreg;
        __syncthreads();
        if (kt + 64 < SS) {
            kreg = *(const uint4*)(kbase + (size_t)(kt + 64 + srow) * DKK + scol);
            vreg = *(const uint4*)(vbase + (size_t)srow * SS + kt + 64 + scol);
        }

        // S = Q K^T
        f32x4 s[4];
#pragma unroll
        for (int n = 0; n < 4; n++) s[n] = (f32x4){0.f, 0.f, 0.f, 0.f};
        __builtin_amdgcn_s_setprio(1);
#pragma unroll
        for (int n = 0; n < 4; n++)
#pragma unroll
            for (int ks = 0; ks < 2; ks++) {
                bf16x8 kf = *(const bf16x8*)&Ksm[(n * 16 + lr) * 72 + ks * 32 + lg * 8];
                s[n] = __builtin_amdgcn_mfma_f32_16x16x32_bf16(qf[ks], kf, s[n], 0, 0, 0);
            }
        __builtin_amdgcn_s_setprio(0);

        // defer-max softmax: per-lane max check; cross-lane reduce+rescale only when needed
#pragma unroll
        for (int n = 0; n < 4; n++) s[n] *= SC;
        float mx[4];
#pragma unroll
        for (int r = 0; r < 4; r++)
            mx[r] = fmaxf(fmaxf(s[0][r], s[1][r]), fmaxf(s[2][r], s[3][r]));
        bool ok = true;
#pragma unroll
        for (int r = 0; r < 4; r++) ok = ok && (mx[r] <= m_run[r] + 8.f);
        if (!__all(ok)) {
#pragma unroll
            for (int r = 0; r < 4; r++) {
                float t2 = mx[r];
                t2 = fmaxf(t2, __shfl_xor(t2, 1, 16));
                t2 = fmaxf(t2, __shfl_xor(t2, 2, 16));
                t2 = fmaxf(t2, __shfl_xor(t2, 4, 16));
                t2 = fmaxf(t2, __shfl_xor(t2, 8, 16));
                float mn = fmaxf(m_run[r], t2);
                float fc = fast_exp2(m_run[r] - mn);
                m_run[r] = mn;
                l_run[r] *= fc;
#pragma unroll
                for (int j = 0; j < 4; j++) accO[j][r] *= fc;
            }
        }
#pragma unroll
        for (int n = 0; n < 4; n++)
#pragma unroll
            for (int r = 0; r < 4; r++) {
                float p = fast_exp2(s[n][r] - m_run[r]);
                l_run[r] += p;
                s[n][r] = p;
            }

        // P -> per-wave LDS region (same-wave producer/consumer; no barrier needed)
#pragma unroll
        for (int n = 0; n < 4; n++)
#pragma unroll
            for (int r = 0; r < 4; r++)
                Pw[(lg * 4 + r) * 68 + n * 16 + lr] = __float2bfloat16(s[n][r]);

        // O += P V
        bf16x8 pa[2];
#pragma unroll
        for (int ks = 0; ks < 2; ks++)
            pa[ks] = *(const bf16x8*)&Pw[lr * 68 + ks * 32 + lg * 8];
        __builtin_amdgcn_s_setprio(1);
#pragma unroll
        for (int j = 0; j < 4; j++)
#pragma unroll
            for (int ks = 0; ks < 2; ks++) {
                bf16x8 vb8 = *(const bf16x8*)&Vtm[(j * 16 + lr) * 72 + ks * 32 + lg * 8];
                accO[j] = __builtin_amdgcn_mfma_f32_16x16x32_bf16(pa[ks], vb8, accO[j], 0, 0, 0);
            }
        __builtin_amdgcn_s_setprio(0);
    }

    // final cross-lane reduction of per-lane l partials
    float inv[4];
#pragma unroll
    for (int r = 0; r < 4; r++) {
        float ls = l_run[r];
        ls += __shfl_xor(ls, 1, 16);
        ls += __shfl_xor(ls, 2, 16);
        ls += __shfl_xor(ls, 4, 16);
        ls += __shfl_xor(ls, 8, 16);
        inv[r] = 1.f / ls;
    }
#pragma unroll
    for (int j = 0; j < 4; j++)
#pragma unroll
        for (int r = 0; r < 4; r++) {
            int row = q0 + w * 16 + lg * 4 + r;
            ao[((size_t)(b * SS) + row) * EE + hh * 64 + j * 16 + lr] = __float2bfloat16(accO[j][r] * inv[r]);
        }
}

// ------- layernorm(x + res): one WAVE per row, float4 loads, shuffle-only reduction -------
__global__ __launch_bounds__(256) void ln_kernel(float* __restrict__ x,
                                                 const float* __restrict__ res,
                                                 const float* __restrict__ g,
                                                 const float* __restrict__ beta,
                                                 bf16* __restrict__ xb) {
    int t = threadIdx.x, lane = t & 63, wv = t >> 6;
    int row = blockIdx.x * 4 + wv;
    float* xr = x + (size_t)row * EE;
    const float* rr = res + (size_t)row * EE;
    int c0 = lane * 8;
    float4 a0 = *(const float4*)(xr + c0);
    float4 a1 = *(const float4*)(xr + c0 + 4);
    float4 b0 = *(const float4*)(rr + c0);
    float4 b1 = *(const float4*)(rr + c0 + 4);
    float v[8];
    v[0] = a0.x + b0.x; v[1] = a0.y + b0.y; v[2] = a0.z + b0.z; v[3] = a0.w + b0.w;
    v[4] = a1.x + b1.x; v[5] = a1.y + b1.y; v[6] = a1.z + b1.z; v[7] = a1.w + b1.w;
    float s = 0.f;
#pragma unroll
    for (int i = 0; i < 8; i++) s += v[i];
#pragma unroll
    for (int m = 1; m < 64; m <<= 1) s += __shfl_xor(s, m, 64);
    float mean = s * (1.f / EE);
    float qv = 0.f;
#pragma unroll
    for (int i = 0; i < 8; i++) { v[i] -= mean; qv += v[i] * v[i]; }
#pragma unroll
    for (int m = 1; m < 64; m <<= 1) qv += __shfl_xor(qv, m, 64);
    float rs = rsqrtf(qv * (1.f / EE) + 1e-5f);
    float4 gg0 = *(const float4*)(g + c0);
    float4 gg1 = *(const float4*)(g + c0 + 4);
    float4 bb0 = *(const float4*)(beta + c0);
    float4 bb1 = *(const float4*)(beta + c0 + 4);
    float o[8];
    o[0] = v[0] * rs * gg0.x + bb0.x; o[1] = v[1] * rs * gg0.y + bb0.y;
    o[2] = v[2] * rs * gg0.z + bb0.z; o[3] = v[3] * rs * gg0.w + bb0.w;
    o[4] = v[4] * rs * gg1.x + bb1.x; o[5] = v[5] * rs * gg1.y + bb1.y;
    o[6] = v[6] * rs * gg1.z + bb1.z; o[7] = v[7] * rs * gg1.w + bb1.w;
    *(float4*)(xr + c0)     = make_float4(o[0], o[1], o[2], o[3]);
    *(float4*)(xr + c0 + 4) = make_float4(o[4], o[5], o[6], o[7]);
    ushort4 pk0, pk1;
    pk0.x = bf16bits(o[0]); pk0.y = bf16bits(o[1]); pk0.z = bf16bits(o[2]); pk0.w = bf16bits(o[3]);
    pk1.x = bf16bits(o[4]); pk1.y = bf16bits(o[5]); pk1.z = bf16bits(o[6]); pk1.w = bf16bits(o[7]);
    bf16* xbr = xb + (size_t)row * EE + c0;
    *(ushort4*)xbr       = pk0;
    *(ushort4*)(xbr + 4) = pk1;
}

// ---------------- mean over S (two stage) + classifier ----------------
__global__ __launch_bounds__(256) void meanpart_kernel(const float* __restrict__ x,
                                                       float* __restrict__ part) {
    int b = blockIdx.y, c = blockIdx.x;
    int t = threadIdx.x;
    float2 acc = make_float2(0.f, 0.f);
    for (int s = c * 32; s < c * 32 + 32; s++) {
        float2 v = *(const float2*)(x + ((size_t)b * SS + s) * EE + t * 2);
        acc.x += v.x; acc.y += v.y;
    }
    *(float2*)(part + (size_t)(b * 64 + c) * EE + t * 2) = acc;
}

__global__ __launch_bounds__(256) void meancls_kernel(const float* __restrict__ part,
                                                      const float* __restrict__ cw,
                                                      const float* __restrict__ cb,
                                                      float* __restrict__ out) {
    int b = blockIdx.x;
    int t = threadIdx.x;
    __shared__ float xm[EE];
    float2 acc = make_float2(0.f, 0.f);
    for (int i = 0; i < 64; i++) {
        float2 v = *(const float2*)(part + (size_t)(b * 64 + i) * EE + t * 2);
        acc.x += v.x; acc.y += v.y;
    }
    xm[t * 2]     = acc.x * (1.f / SS);
    xm[t * 2 + 1] = acc.y * (1.f / SS);
    __syncthreads();
    if (t < CC) {
        float a = cb[t];
        for (int e = 0; e < EE; e++) a += xm[e] * cw[e * CC + t];
        out[b * CC + t] = a;
    }
}

extern "C" void kernel_launch(void* const* d_in, const int* in_sizes, int n_in,
                              void* d_out, int out_size, void* d_ws, size_t ws_size,
                              hipStream_t stream) {
    (void)in_sizes; (void)n_in; (void)out_size; (void)ws_size;
    const int*   tokens = (const int*)d_in[0];
    const float* emb    = (const float*)d_in[1];
    const float* Wq     = (const float*)d_in[2];
    const float* Wk     = (const float*)d_in[3];
    const float* Wv     = (const float*)d_in[4];
    const float* Wo     = (const float*)d_in[5];
    const float* qh_w   = (const float*)d_in[6];
    const float* qh_b   = (const float*)d_in[7];
    const float* kh_w   = (const float*)d_in[8];
    const float* kh_b   = (const float*)d_in[9];
    const float* vh_w   = (const float*)d_in[10];
    const float* vh_b   = (const float*)d_in[11];
    const float* ln1_g  = (const float*)d_in[12];
    const float* ln1_b  = (const float*)d_in[13];
    const float* ln2_g  = (const float*)d_in[14];
    const float* ln2_b  = (const float*)d_in[15];
    const float* f_w1   = (const float*)d_in[16];
    const float* f_b1   = (const float*)d_in[17];
    const float* f_w2   = (const float*)d_in[18];
    const float* f_b2   = (const float*)d_in[19];
    const float* cls_w  = (const float*)d_in[20];
    const float* cls_b  = (const float*)d_in[21];

    const size_t nBSF = (size_t)BB * SS * FFF;
    float* x    = (float*)d_ws;
    float* t0   = x + NBSE;
    float* part = t0 + NBSE;
    bf16* xb    = (bf16*)(part + (size_t)BB * 64 * EE);
    bf16* qb    = xb + NBSE;
    bf16* kb    = qb + NBSE;
    bf16* vb    = kb + NBSE;
    bf16* vTb   = vb + NBSE;
    bf16* ao    = vTb + NBSE;
    bf16* ffnb  = ao + NBSE;
    bf16* WqkvT = ffnb + nBSF;
    bf16* WoT   = WqkvT + (size_t)NBB * 3 * EE * EE;
    bf16* fw1T  = WoT + (size_t)NBB * EE * EE;
    bf16* fw2T  = fw1T + (size_t)NBB * EE * FFF;
    bf16* qhT   = fw2T + (size_t)NBB * EE * FFF;
    bf16* khT   = qhT + (size_t)NBB * LL * HH * DKK * DKK;
    bf16* vhT   = khT + (size_t)NBB * LL * HH * DKK * DKK;

    const int M = BB * SS;   // 8192
    const size_t zQKV = (size_t)3 * EE * EE;

    transpose_to_bf16<<<dim3(EE / 64, EE / 64, NBB), 256, 0, stream>>>(Wq, WqkvT, EE, EE, zQKV, 0);
    transpose_to_bf16<<<dim3(EE / 64, EE / 64, NBB), 256, 0, stream>>>(Wk, WqkvT, EE, EE, zQKV, EE);
    transpose_to_bf16<<<dim3(EE / 64, EE / 64, NBB), 256, 0, stream>>>(Wv, WqkvT, EE, EE, zQKV, 2 * EE);
    transpose_to_bf16<<<dim3(EE / 64, EE / 64, NBB), 256, 0, stream>>>(Wo, WoT, EE, EE, (size_t)EE * EE, 0);
    transpose_to_bf16<<<dim3(FFF / 64, EE / 64, NBB), 256, 0, stream>>>(f_w1, fw1T, EE, FFF, (size_t)EE * FFF, 0);
    transpose_to_bf16<<<dim3(EE / 64, FFF / 64, NBB), 256, 0, stream>>>(f_w2, fw2T, FFF, EE, (size_t)EE * FFF, 0);
    transpose_to_bf16<<<dim3(1, 1, NBB * LL * HH), 256, 0, stream>>>(qh_w, qhT, DKK, DKK, (size_t)DKK * DKK, 0);
    transpose_to_bf16<<<dim3(1, 1, NBB * LL * HH), 256, 0, stream>>>(kh_w, khT, DKK, DKK, (size_t)DKK * DKK, 0);
    transpose_to_bf16<<<dim3(1, 1, NBB * LL * HH), 256, 0, stream>>>(vh_w, vhT, DKK, DKK, (size_t)DKK * DKK, 0);

    embed_kernel<<<(BB * SS * EE / 2 + 255) / 256, 256, 0, stream>>>(tokens, emb, x, xb);

    for (int blk = 0; blk < NBB; blk++) {
        dim3 gEE64(EE / 128, M / 64);    // (4,128) = 512 wgs
        dim3 gQKV(3 * EE / 128, M / 128);// (12,64)
        dim3 gFF(FFF / 128, M / 128);    // (16,64)
        const size_t wE = (size_t)blk * EE * EE;
        const size_t qwOff = (size_t)blk * LL * HH * DKK * DKK;
        const size_t qbOff = (size_t)blk * LL * HH * DKK;

        gemm_bf16<<<gQKV, 256, 0, stream>>>(xb, WqkvT + blk * zQKV, nullptr, qb, M, 3 * EE, EE, GF_SCATTER3);

        quantum_mfma<<<dim3(SS / 128, BB * HH, 3), 256, 0, stream>>>(
            qb, kb, vb, vTb, qhT + qwOff, khT + qwOff, vhT + qwOff,
            qh_b + qbOff, kh_b + qbOff, vh_b + qbOff);

        attn_mfma<<<dim3(512), 512, 0, stream>>>(qb, kb, vTb, ao);

        gemm_bf16_m64<<<gEE64, 256, 0, stream>>>(ao, WoT + wE, nullptr, t0, M, EE, EE, 0);
        ln_kernel<<<M / 4, 256, 0, stream>>>(x, t0, ln1_g + blk * EE, ln1_b + blk * EE, xb);

        gemm_bf16<<<gFF, 256, 0, stream>>>(xb, fw1T + (size_t)blk * EE * FFF, f_b1 + blk * FFF, ffnb, M, FFF, EE, GF_RELU | GF_OUTBF16);
        gemm_bf16_m64<<<gEE64, 256, 0, stream>>>(ffnb, fw2T + (size_t)blk * EE * FFF, f_b2 + blk * EE, t0, M, EE, FFF, 0);
        ln_kernel<<<M / 4, 256, 0, stream>>>(x, t0, ln2_g + blk * EE, ln2_b + blk * EE, xb);
    }

    meanpart_kernel<<<dim3(64, BB), 256, 0, stream>>>(x, part);
    meancls_kernel<<<BB, 256, 0, stream>>>(part, cls_w, cls_b, (float*)d_out);
}

// Round 20
// 956.433 us; speedup vs baseline: 1.0744x; 1.0313x over previous
//
#include <hip/hip_runtime.h>
#include <hip/hip_bf16.h>
#include <math.h>

#define BB 4
#define SS 2048
#define EE 512
#define HH 8
#define DKK 64
#define LL 2
#define NBB 4
#define FFF 2048
#define CC 4
#define NBSE ((size_t)BB * SS * EE)

typedef __attribute__((ext_vector_type(8))) short bf16x8;
typedef __attribute__((ext_vector_type(4))) float f32x4;
using bf16 = __hip_bfloat16;

__device__ __forceinline__ float fast_exp2(float x) { return __builtin_amdgcn_exp2f(x); }

__device__ __forceinline__ void gload16(const bf16* g, bf16* l) {
    __builtin_amdgcn_global_load_lds((const __attribute__((address_space(1))) void*)g,
                                     (__attribute__((address_space(3))) void*)l, 16, 0, 0);
}
__device__ __forceinline__ unsigned short bf16bits(float f) {
    bf16 h = __float2bfloat16(f);
    return *(unsigned short*)&h;
}

// ---------------- embedding + positional encoding (f32 + bf16 copies) ----------------
__global__ __launch_bounds__(256) void embed_kernel(const int* __restrict__ tokens,
                                                    const float* __restrict__ emb,
                                                    float* __restrict__ x,
                                                    bf16* __restrict__ xb) {
    int i = blockIdx.x * blockDim.x + threadIdx.x;
    int total = BB * SS * EE / 2;
    if (i >= total) return;
    int pi  = i & (EE / 2 - 1);
    int row = i >> 8;
    int s   = row & (SS - 1);
    int tok = tokens[row];
    int e0  = pi * 2;
    const float kln = 9.210340371976184f / (float)EE;
    float arg = (float)s * expf(-(float)e0 * kln);
    float2 ev = *(const float2*)(emb + (size_t)tok * EE + e0);
    float2 o;
    o.x = ev.x + sinf(arg);
    o.y = ev.y + cosf(arg);
    *(float2*)(x + (size_t)row * EE + e0) = o;
    xb[(size_t)row * EE + e0]     = __float2bfloat16(o.x);
    xb[(size_t)row * EE + e0 + 1] = __float2bfloat16(o.y);
}

// ------- f32 [z][K][N] -> bf16 [z*zstride + (row_off+n)*K + k] transpose/cast -------
__global__ __launch_bounds__(256) void transpose_to_bf16(const float* __restrict__ in,
                                                         bf16* __restrict__ out,
                                                         int K, int N,
                                                         size_t zstride, int row_off) {
    const float* src = in + (size_t)blockIdx.z * K * N;
    bf16* dst = out + (size_t)blockIdx.z * zstride;
    int r0 = blockIdx.y * 64, c0 = blockIdx.x * 64;
    __shared__ float tl[64][65];
    int t = threadIdx.x;
    int lr = t >> 4, lc = (t & 15) * 4;
#pragma unroll
    for (int i = 0; i < 4; i++) {
        float4 v = *(const float4*)(src + (size_t)(r0 + lr + i * 16) * N + c0 + lc);
        tl[lr + i * 16][lc + 0] = v.x;
        tl[lr + i * 16][lc + 1] = v.y;
        tl[lr + i * 16][lc + 2] = v.z;
        tl[lr + i * 16][lc + 3] = v.w;
    }
    __syncthreads();
#pragma unroll
    for (int i = 0; i < 4; i++) {
        int n = lr + i * 16;
#pragma unroll
        for (int j = 0; j < 4; j++)
            dst[(size_t)(row_off + c0 + n) * K + r0 + lc + j] = __float2bfloat16(tl[lc + j][n]);
    }
}

// ---- fold quantum: W01 = W0 @ W1 (f32), beff = b0 @ W1 + b1 ----
// w layout [NB][L][H][64][64]; b layout [NB][L][H][64]
__global__ __launch_bounds__(256) void fold_w01(const float* __restrict__ qw, const float* __restrict__ kw, const float* __restrict__ vw,
                                                const float* __restrict__ qbv, const float* __restrict__ kbv, const float* __restrict__ vbv,
                                                float* __restrict__ w01, float* __restrict__ beff) {
    int h = blockIdx.x, z = blockIdx.y, blk = blockIdx.z;
    const float* w  = z == 0 ? qw  : (z == 1 ? kw  : vw);
    const float* bi = z == 0 ? qbv : (z == 1 ? kbv : vbv);
    const float* W0 = w + ((size_t)(blk * LL + 0) * HH + h) * 4096;
    const float* W1 = w + ((size_t)(blk * LL + 1) * HH + h) * 4096;
    __shared__ float s0[64 * 64];
    __shared__ float s1[64 * 64];
    int t = threadIdx.x;
    for (int i = t; i < 4096; i += 256) { s0[i] = W0[i]; s1[i] = W1[i]; }
    __syncthreads();
    int d = t >> 2, e0 = (t & 3) * 16;
    float acc[16] = {};
    for (int c = 0; c < 64; c++) {
        float a = s0[d * 64 + c];
#pragma unroll
        for (int e = 0; e < 16; e++) acc[e] += a * s1[c * 64 + e0 + e];
    }
    float* wout = w01 + ((size_t)(blk * 3 + z) * HH + h) * 4096;
#pragma unroll
    for (int e = 0; e < 16; e++) wout[d * 64 + e0 + e] = acc[e];
    if (t < 64) {
        const float* b0 = bi + ((size_t)(blk * LL + 0) * HH + h) * 64;
        const float* b1 = bi + ((size_t)(blk * LL + 1) * HH + h) * 64;
        float a = b1[t];
        for (int c = 0; c < 64; c++) a += b0[c] * s1[c * 64 + t];
        beff[(size_t)blk * 1536 + z * 512 + h * 64 + t] = a;
    }
}

// ---- fold quantum into QKV weights: WqkvT[blk][z*512+h*64+dk][k] = bf16(sum_d Wz[k][h*64+d]*W01[d][dk]) ----
__global__ __launch_bounds__(256) void fold_wqkv(const float* __restrict__ Wq, const float* __restrict__ Wk, const float* __restrict__ Wv,
                                                 const float* __restrict__ w01, bf16* __restrict__ WqkvT) {
    int kc = blockIdx.x;          // k-chunk (0..7)
    int h  = blockIdx.y;
    int zb = blockIdx.z;          // blk*3 + z
    int blk = zb / 3, z = zb % 3;
    const float* Wz  = (z == 0 ? Wq : (z == 1 ? Wk : Wv)) + (size_t)blk * EE * EE;
    const float* Wp  = w01 + ((size_t)zb * HH + h) * 4096;
    __shared__ float sw[64 * 64];   // [kk][d]
    __shared__ float sp[64 * 64];   // [d][dk]
    int t = threadIdx.x;
    for (int i = t; i < 4096; i += 256) {
        int kk = i >> 6, d = i & 63;
        sw[i] = Wz[(size_t)(kc * 64 + kk) * EE + h * 64 + d];
        sp[i] = Wp[i];
    }
    __syncthreads();
    int kk = t >> 2, dk0 = (t & 3) * 16;
    float acc[16] = {};
    for (int d = 0; d < 64; d++) {
        float a = sw[kk * 64 + d];
#pragma unroll
        for (int e = 0; e < 16; e++) acc[e] += a * sp[d * 64 + dk0 + e];
    }
    bf16* outb = WqkvT + (size_t)blk * 3 * EE * EE;
    int k = kc * 64 + kk;
#pragma unroll
    for (int e = 0; e < 16; e++)
        outb[(size_t)(z * 512 + h * 64 + dk0 + e) * EE + k] = __float2bfloat16(acc[e]);
}

// ---- v [bh][s][dk] -> vT [bh][dk][s] via LDS 64x64 tile ----
__global__ __launch_bounds__(256) void vtrans_kernel(const bf16* __restrict__ v, bf16* __restrict__ vT) {
    int s0 = blockIdx.x * 64, bh = blockIdx.y;
    __shared__ bf16 vt[64 * 72];
    int t = threadIdx.x;
    int r = t >> 2, c0 = (t & 3) * 16;
    const bf16* src = v + ((size_t)bh * SS + s0) * DKK;
    uint4 v0 = *(const uint4*)(src + (size_t)r * DKK + c0);
    uint4 v1 = *(const uint4*)(src + (size_t)r * DKK + c0 + 8);
    const unsigned short* e0 = (const unsigned short*)&v0;
    const unsigned short* e1 = (const unsigned short*)&v1;
#pragma unroll
    for (int j = 0; j < 8; j++) {
        ((unsigned short*)vt)[(c0 + j) * 72 + r]     = e0[j];
        ((unsigned short*)vt)[(c0 + 8 + j) * 72 + r] = e1[j];
    }
    __syncthreads();
    bf16* dst = vT + (size_t)bh * DKK * SS + s0;
    *(uint4*)(dst + (size_t)r * SS + c0)     = *(uint4*)&vt[r * 72 + c0];
    *(uint4*)(dst + (size_t)r * SS + c0 + 8) = *(uint4*)&vt[r * 72 + c0 + 8];
}

// ---------------- bf16 MFMA GEMM (128x128 tile): C[M,N] = A[M,K] @ BT[N,K]^T ----------------
#define GF_RELU 1
#define GF_SCATTER3 2
#define GF_OUTBF16 4
__global__ __launch_bounds__(256) void gemm_bf16(const bf16* __restrict__ A,
                                                 const bf16* __restrict__ BT,
                                                 const float* __restrict__ bias,
                                                 void* __restrict__ C,
                                                 int M, int N, int K, int flags) {
    __shared__ __align__(16) bf16 Asm[128 * 32];
    __shared__ __align__(16) bf16 Bsm[128 * 32];
    int t = threadIdx.x;
    int l = t & 63, w = t >> 6;
    int nbx = gridDim.x;
    int lin = blockIdx.y * nbx + blockIdx.x;
    int cpx = (nbx * gridDim.y) >> 3;
    int swz = (lin & 7) * cpx + (lin >> 3);
    int bm = (swz / nbx) * 128, bn = (swz % nbx) * 128;
    int wr = (w >> 1) * 64, wc = (w & 1) * 64;
    int lr = l & 15, lg = l >> 4;
    int ca = w * 2;
    int sr = l >> 2, sk = (l & 3) * 8;
    const bf16* ga  = A  + (size_t)(bm + ca * 16 + sr) * K + sk;
    const bf16* ga2 = ga + (size_t)16 * K;
    const bf16* gb  = BT + (size_t)(bn + ca * 16 + sr) * K + sk;
    const bf16* gb2 = gb + (size_t)16 * K;

    f32x4 acc[4][4];
#pragma unroll
    for (int m = 0; m < 4; m++)
#pragma unroll
        for (int n = 0; n < 4; n++) acc[m][n] = (f32x4){0.f, 0.f, 0.f, 0.f};

    for (int k0 = 0; k0 < K; k0 += 32) {
        __syncthreads();
        gload16(ga + k0,  &Asm[ca * 512]);
        gload16(ga2 + k0, &Asm[ca * 512 + 512]);
        gload16(gb + k0,  &Bsm[ca * 512]);
        gload16(gb2 + k0, &Bsm[ca * 512 + 512]);
        __syncthreads();
        bf16x8 af[4], bfr[4];
#pragma unroll
        for (int m = 0; m < 4; m++)
            af[m] = *(const bf16x8*)&Asm[(wr + m * 16 + lr) * 32 + lg * 8];
#pragma unroll
        for (int n = 0; n < 4; n++)
            bfr[n] = *(const bf16x8*)&Bsm[(wc + n * 16 + lr) * 32 + lg * 8];
#pragma unroll
        for (int m = 0; m < 4; m++)
#pragma unroll
            for (int n = 0; n < 4; n++)
                acc[m][n] = __builtin_amdgcn_mfma_f32_16x16x32_bf16(af[m], bfr[n], acc[m][n], 0, 0, 0);
    }

#pragma unroll
    for (int m = 0; m < 4; m++) {
        int row = bm + wr + m * 16 + lg * 4;
#pragma unroll
        for (int n = 0; n < 4; n++) {
            int col = bn + wc + n * 16 + lr;
            float bv = bias ? bias[col] : 0.f;
#pragma unroll
            for (int r = 0; r < 4; r++) {
                float v = acc[m][n][r] + bv;
                if (flags & GF_RELU) v = fmaxf(v, 0.f);
                int rr = row + r;
                if (flags & GF_SCATTER3) {
                    int tsel = col >> 9;
                    int b = rr >> 11, s = rr & (SS - 1);
                    int h = (col >> 6) & 7, dk = col & 63;
                    ((bf16*)C)[tsel * NBSE + (((size_t)(b * HH + h) * SS + s) << 6) + dk] = __float2bfloat16(v);
                } else if (flags & GF_OUTBF16) {
                    ((bf16*)C)[(size_t)rr * N + col] = __float2bfloat16(v);
                } else {
                    ((float*)C)[(size_t)rr * N + col] = v;
                }
            }
        }
    }
}

// ------- bf16 MFMA GEMM (64x128 tile, for N=512 shapes: 2 blocks/CU instead of 1) -------
__global__ __launch_bounds__(256) void gemm_bf16_m64(const bf16* __restrict__ A,
                                                     const bf16* __restrict__ BT,
                                                     const float* __restrict__ bias,
                                                     void* __restrict__ C,
                                                     int M, int N, int K, int flags) {
    __shared__ __align__(16) bf16 Asm[64 * 32];
    __shared__ __align__(16) bf16 Bsm[128 * 32];
    int t = threadIdx.x;
    int l = t & 63, w = t >> 6;
    int nbx = gridDim.x;
    int lin = blockIdx.y * nbx + blockIdx.x;
    int cpx = (nbx * gridDim.y) >> 3;
    int swz = (lin & 7) * cpx + (lin >> 3);
    int bm = (swz / nbx) * 64, bn = (swz % nbx) * 128;
    int wr = (w >> 1) * 32, wc = (w & 1) * 64;
    int lr = l & 15, lg = l >> 4;
    int ca = w * 2;
    int sr = l >> 2, sk = (l & 3) * 8;
    const bf16* ga  = A  + (size_t)(bm + w * 16 + sr) * K + sk;
    const bf16* gb  = BT + (size_t)(bn + ca * 16 + sr) * K + sk;
    const bf16* gb2 = gb + (size_t)16 * K;

    f32x4 acc[2][4];
#pragma unroll
    for (int m = 0; m < 2; m++)
#pragma unroll
        for (int n = 0; n < 4; n++) acc[m][n] = (f32x4){0.f, 0.f, 0.f, 0.f};

    for (int k0 = 0; k0 < K; k0 += 32) {
        __syncthreads();
        gload16(ga + k0,  &Asm[w * 512]);
        gload16(gb + k0,  &Bsm[ca * 512]);
        gload16(gb2 + k0, &Bsm[ca * 512 + 512]);
        __syncthreads();
        bf16x8 af[2], bfr[4];
#pragma unroll
        for (int m = 0; m < 2; m++)
            af[m] = *(const bf16x8*)&Asm[(wr + m * 16 + lr) * 32 + lg * 8];
#pragma unroll
        for (int n = 0; n < 4; n++)
            bfr[n] = *(const bf16x8*)&Bsm[(wc + n * 16 + lr) * 32 + lg * 8];
#pragma unroll
        for (int m = 0; m < 2; m++)
#pragma unroll
            for (int n = 0; n < 4; n++)
                acc[m][n] = __builtin_amdgcn_mfma_f32_16x16x32_bf16(af[m], bfr[n], acc[m][n], 0, 0, 0);
    }

#pragma unroll
    for (int m = 0; m < 2; m++) {
        int row = bm + wr + m * 16 + lg * 4;
#pragma unroll
        for (int n = 0; n < 4; n++) {
            int col = bn + wc + n * 16 + lr;
            float bv = bias ? bias[col] : 0.f;
#pragma unroll
            for (int r = 0; r < 4; r++) {
                float v = acc[m][n][r] + bv;
                if (flags & GF_RELU) v = fmaxf(v, 0.f);
                int rr = row + r;
                if (flags & GF_OUTBF16) {
                    ((bf16*)C)[(size_t)rr * N + col] = __float2bfloat16(v);
                } else {
                    ((float*)C)[(size_t)rr * N + col] = v;
                }
            }
        }
    }
}

// ---- flash attention: 8 waves, 128 q/block, KVBLK=64, defer-max + deferred l-sum (R16) ----
// q,k: [B,H,S,DK] bf16; vT: [B,H,DK,S] bf16; ao: [B,S,E] bf16
__global__ __launch_bounds__(512) __attribute__((amdgpu_waves_per_eu(6, 6)))
void attn_mfma(const bf16* __restrict__ q,
               const bf16* __restrict__ k,
               const bf16* __restrict__ vT,
               bf16* __restrict__ ao) {
    __shared__ __align__(16) bf16 Ksm[64 * 72];
    __shared__ __align__(16) bf16 Vtm[64 * 72];
    __shared__ __align__(16) bf16 Psm[8 * 16 * 68];
    int wg  = blockIdx.x;
    int nw  = (wg & 7) * 64 + (wg >> 3);   // XCD-bijective remap (512 %8==0)
    int bh  = nw >> 4;
    int q0  = (nw & 15) * 128;
    int b = bh >> 3, hh = bh & 7;
    int t = threadIdx.x, l = t & 63, w = t >> 6;
    int lr = l & 15, lg = l >> 4;
    bf16* Pw = &Psm[w * 16 * 68];

    bf16x8 qf[2];
#pragma unroll
    for (int ks = 0; ks < 2; ks++)
        qf[ks] = *(const bf16x8*)(q + ((size_t)bh * SS + q0 + w * 16 + lr) * DKK + ks * 32 + lg * 8);

    float m_run[4] = {-INFINITY, -INFINITY, -INFINITY, -INFINITY};
    float l_run[4] = {0.f, 0.f, 0.f, 0.f};
    f32x4 accO[4];
#pragma unroll
    for (int j = 0; j < 4; j++) accO[j] = (f32x4){0.f, 0.f, 0.f, 0.f};

    const bf16* kbase = k  + (size_t)bh * SS * DKK;
    const bf16* vbase = vT + (size_t)bh * DKK * SS;
    int srow = t >> 3, scol = (t & 7) * 8;

    uint4 kreg, vreg;
    kreg = *(const uint4*)(kbase + (size_t)srow * DKK + scol);
    vreg = *(const uint4*)(vbase + (size_t)srow * SS + scol);

    const float SC = 0.180336879f;   // 0.125 * log2(e)

    for (int kt = 0; kt < SS; kt += 64) {
        __syncthreads();
        *(uint4*)&Ksm[srow * 72 + scol] = kreg;
        *(uint4*)&Vtm[srow * 72 + scol] = vreg;
        __syncthreads();
        if (kt + 64 < SS) {
            kreg = *(const uint4*)(kbase + (size_t)(kt + 64 + srow) * DKK + scol);
            vreg = *(const uint4*)(vbase + (size_t)srow * SS + kt + 64 + scol);
        }

        // S = Q K^T
        f32x4 s[4];
#pragma unroll
        for (int n = 0; n < 4; n++) s[n] = (f32x4){0.f, 0.f, 0.f, 0.f};
        __builtin_amdgcn_s_setprio(1);
#pragma unroll
        for (int n = 0; n < 4; n++)
#pragma unroll
            for (int ks = 0; ks < 2; ks++) {
                bf16x8 kf = *(const bf16x8*)&Ksm[(n * 16 + lr) * 72 + ks * 32 + lg * 8];
                s[n] = __builtin_amdgcn_mfma_f32_16x16x32_bf16(qf[ks], kf, s[n], 0, 0, 0);
            }
        __builtin_amdgcn_s_setprio(0);

        // defer-max softmax: per-lane max check; cross-lane reduce+rescale only when needed
#pragma unroll
        for (int n = 0; n < 4; n++) s[n] *= SC;
        float mx[4];
#pragma unroll
        for (int r = 0; r < 4; r++)
            mx[r] = fmaxf(fmaxf(s[0][r], s[1][r]), fmaxf(s[2][r], s[3][r]));
        bool ok = true;
#pragma unroll
        for (int r = 0; r < 4; r++) ok = ok && (mx[r] <= m_run[r] + 8.f);
        if (!__all(ok)) {
#pragma unroll
            for (int r = 0; r < 4; r++) {
                float t2 = mx[r];
                t2 = fmaxf(t2, __shfl_xor(t2, 1, 16));
                t2 = fmaxf(t2, __shfl_xor(t2, 2, 16));
                t2 = fmaxf(t2, __shfl_xor(t2, 4, 16));
                t2 = fmaxf(t2, __shfl_xor(t2, 8, 16));
                float mn = fmaxf(m_run[r], t2);
                float fc = fast_exp2(m_run[r] - mn);
                m_run[r] = mn;
                l_run[r] *= fc;
#pragma unroll
                for (int j = 0; j < 4; j++) accO[j][r] *= fc;
            }
        }
#pragma unroll
        for (int n = 0; n < 4; n++)
#pragma unroll
            for (int r = 0; r < 4; r++) {
                float p = fast_exp2(s[n][r] - m_run[r]);
                l_run[r] += p;
                s[n][r] = p;
            }

        // P -> per-wave LDS region (same-wave producer/consumer; no barrier needed)
#pragma unroll
        for (int n = 0; n < 4; n++)
#pragma unroll
            for (int r = 0; r < 4; r++)
                Pw[(lg * 4 + r) * 68 + n * 16 + lr] = __float2bfloat16(s[n][r]);

        // O += P V
        bf16x8 pa[2];
#pragma unroll
        for (int ks = 0; ks < 2; ks++)
            pa[ks] = *(const bf16x8*)&Pw[lr * 68 + ks * 32 + lg * 8];
        __builtin_amdgcn_s_setprio(1);
#pragma unroll
        for (int j = 0; j < 4; j++)
#pragma unroll
            for (int ks = 0; ks < 2; ks++) {
                bf16x8 vb8 = *(const bf16x8*)&Vtm[(j * 16 + lr) * 72 + ks * 32 + lg * 8];
                accO[j] = __builtin_amdgcn_mfma_f32_16x16x32_bf16(pa[ks], vb8, accO[j], 0, 0, 0);
            }
        __builtin_amdgcn_s_setprio(0);
    }

    // final cross-lane reduction of per-lane l partials
    float inv[4];
#pragma unroll
    for (int r = 0; r < 4; r++) {
        float ls = l_run[r];
        ls += __shfl_xor(ls, 1, 16);
        ls += __shfl_xor(ls, 2, 16);
        ls += __shfl_xor(ls, 4, 16);
        ls += __shfl_xor(ls, 8, 16);
        inv[r] = 1.f / ls;
    }
#pragma unroll
    for (int j = 0; j < 4; j++)
#pragma unroll
        for (int r = 0; r < 4; r++) {
            int row = q0 + w * 16 + lg * 4 + r;
            ao[((size_t)(b * SS) + row) * EE + hh * 64 + j * 16 + lr] = __float2bfloat16(accO[j][r] * inv[r]);
        }
}

// ------- layernorm(x + res): one WAVE per row, float4 loads, shuffle-only reduction -------
__global__ __launch_bounds__(256) void ln_kernel(float* __restrict__ x,
                                                 const float* __restrict__ res,
                                                 const float* __restrict__ g,
                                                 const float* __restrict__ beta,
                                                 bf16* __restrict__ xb) {
    int t = threadIdx.x, lane = t & 63, wv = t >> 6;
    int row = blockIdx.x * 4 + wv;
    float* xr = x + (size_t)row * EE;
    const float* rr = res + (size_t)row * EE;
    int c0 = lane * 8;
    float4 a0 = *(const float4*)(xr + c0);
    float4 a1 = *(const float4*)(xr + c0 + 4);
    float4 b0 = *(const float4*)(rr + c0);
    float4 b1 = *(const float4*)(rr + c0 + 4);
    float v[8];
    v[0] = a0.x + b0.x; v[1] = a0.y + b0.y; v[2] = a0.z + b0.z; v[3] = a0.w + b0.w;
    v[4] = a1.x + b1.x; v[5] = a1.y + b1.y; v[6] = a1.z + b1.z; v[7] = a1.w + b1.w;
    float s = 0.f;
#pragma unroll
    for (int i = 0; i < 8; i++) s += v[i];
#pragma unroll
    for (int m = 1; m < 64; m <<= 1) s += __shfl_xor(s, m, 64);
    float mean = s * (1.f / EE);
    float qv = 0.f;
#pragma unroll
    for (int i = 0; i < 8; i++) { v[i] -= mean; qv += v[i] * v[i]; }
#pragma unroll
    for (int m = 1; m < 64; m <<= 1) qv += __shfl_xor(qv, m, 64);
    float rs = rsqrtf(qv * (1.f / EE) + 1e-5f);
    float4 gg0 = *(const float4*)(g + c0);
    float4 gg1 = *(const float4*)(g + c0 + 4);
    float4 bb0 = *(const float4*)(beta + c0);
    float4 bb1 = *(const float4*)(beta + c0 + 4);
    float o[8];
    o[0] = v[0] * rs * gg0.x + bb0.x; o[1] = v[1] * rs * gg0.y + bb0.y;
    o[2] = v[2] * rs * gg0.z + bb0.z; o[3] = v[3] * rs * gg0.w + bb0.w;
    o[4] = v[4] * rs * gg1.x + bb1.x; o[5] = v[5] * rs * gg1.y + bb1.y;
    o[6] = v[6] * rs * gg1.z + bb1.z; o[7] = v[7] * rs * gg1.w + bb1.w;
    *(float4*)(xr + c0)     = make_float4(o[0], o[1], o[2], o[3]);
    *(float4*)(xr + c0 + 4) = make_float4(o[4], o[5], o[6], o[7]);
    ushort4 pk0, pk1;
    pk0.x = bf16bits(o[0]); pk0.y = bf16bits(o[1]); pk0.z = bf16bits(o[2]); pk0.w = bf16bits(o[3]);
    pk1.x = bf16bits(o[4]); pk1.y = bf16bits(o[5]); pk1.z = bf16bits(o[6]); pk1.w = bf16bits(o[7]);
    bf16* xbr = xb + (size_t)row * EE + c0;
    *(ushort4*)xbr       = pk0;
    *(ushort4*)(xbr + 4) = pk1;
}

// ---------------- mean over S (two stage) + classifier ----------------
__global__ __launch_bounds__(256) void meanpart_kernel(const float* __restrict__ x,
                                                       float* __restrict__ part) {
    int b = blockIdx.y, c = blockIdx.x;
    int t = threadIdx.x;
    float2 acc = make_float2(0.f, 0.f);
    for (int s = c * 32; s < c * 32 + 32; s++) {
        float2 v = *(const float2*)(x + ((size_t)b * SS + s) * EE + t * 2);
        acc.x += v.x; acc.y += v.y;
    }
    *(float2*)(part + (size_t)(b * 64 + c) * EE + t * 2) = acc;
}

__global__ __launch_bounds__(256) void meancls_kernel(const float* __restrict__ part,
                                                      const float* __restrict__ cw,
                                                      const float* __restrict__ cb,
                                                      float* __restrict__ out) {
    int b = blockIdx.x;
    int t = threadIdx.x;
    __shared__ float xm[EE];
    float2 acc = make_float2(0.f, 0.f);
    for (int i = 0; i < 64; i++) {
        float2 v = *(const float2*)(part + (size_t)(b * 64 + i) * EE + t * 2);
        acc.x += v.x; acc.y += v.y;
    }
    xm[t * 2]     = acc.x * (1.f / SS);
    xm[t * 2 + 1] = acc.y * (1.f / SS);
    __syncthreads();
    if (t < CC) {
        float a = cb[t];
        for (int e = 0; e < EE; e++) a += xm[e] * cw[e * CC + t];
        out[b * CC + t] = a;
    }
}

extern "C" void kernel_launch(void* const* d_in, const int* in_sizes, int n_in,
                              void* d_out, int out_size, void* d_ws, size_t ws_size,
                              hipStream_t stream) {
    (void)in_sizes; (void)n_in; (void)out_size; (void)ws_size;
    const int*   tokens = (const int*)d_in[0];
    const float* emb    = (const float*)d_in[1];
    const float* Wq     = (const float*)d_in[2];
    const float* Wk     = (const float*)d_in[3];
    const float* Wv     = (const float*)d_in[4];
    const float* Wo     = (const float*)d_in[5];
    const float* qh_w   = (const float*)d_in[6];
    const float* qh_b   = (const float*)d_in[7];
    const float* kh_w   = (const float*)d_in[8];
    const float* kh_b   = (const float*)d_in[9];
    const float* vh_w   = (const float*)d_in[10];
    const float* vh_b   = (const float*)d_in[11];
    const float* ln1_g  = (const float*)d_in[12];
    const float* ln1_b  = (const float*)d_in[13];
    const float* ln2_g  = (const float*)d_in[14];
    const float* ln2_b  = (const float*)d_in[15];
    const float* f_w1   = (const float*)d_in[16];
    const float* f_b1   = (const float*)d_in[17];
    const float* f_w2   = (const float*)d_in[18];
    const float* f_b2   = (const float*)d_in[19];
    const float* cls_w  = (const float*)d_in[20];
    const float* cls_b  = (const float*)d_in[21];

    const size_t nBSF = (size_t)BB * SS * FFF;
    float* x    = (float*)d_ws;
    float* t0   = x + NBSE;
    float* part = t0 + NBSE;
    bf16* xb    = (bf16*)(part + (size_t)BB * 64 * EE);
    bf16* qb    = xb + NBSE;
    bf16* kb    = qb + NBSE;
    bf16* vb    = kb + NBSE;
    bf16* vTb   = vb + NBSE;
    bf16* ao    = vTb + NBSE;
    bf16* ffnb  = ao + NBSE;
    bf16* WqkvT = ffnb + nBSF;
    bf16* WoT   = WqkvT + (size_t)NBB * 3 * EE * EE;
    bf16* fw1T  = WoT + (size_t)NBB * EE * EE;
    bf16* fw2T  = fw1T + (size_t)NBB * EE * FFF;
    float* w01  = (float*)(fw2T + (size_t)NBB * EE * FFF);   // [NB*3][H][64][64] f32
    float* beff = w01 + (size_t)NBB * 3 * HH * DKK * DKK;    // [NB][1536] f32

    const int M = BB * SS;   // 8192
    const size_t zQKV = (size_t)3 * EE * EE;

    // weight prep: fold quantum (pure linear) into QKV projection
    fold_w01<<<dim3(HH, 3, NBB), 256, 0, stream>>>(qh_w, kh_w, vh_w, qh_b, kh_b, vh_b, w01, beff);
    fold_wqkv<<<dim3(8, HH, 3 * NBB), 256, 0, stream>>>(Wq, Wk, Wv, w01, WqkvT);
    transpose_to_bf16<<<dim3(EE / 64, EE / 64, NBB), 256, 0, stream>>>(Wo, WoT, EE, EE, (size_t)EE * EE, 0);
    transpose_to_bf16<<<dim3(FFF / 64, EE / 64, NBB), 256, 0, stream>>>(f_w1, fw1T, EE, FFF, (size_t)EE * FFF, 0);
    transpose_to_bf16<<<dim3(EE / 64, FFF / 64, NBB), 256, 0, stream>>>(f_w2, fw2T, FFF, EE, (size_t)EE * FFF, 0);

    embed_kernel<<<(BB * SS * EE / 2 + 255) / 256, 256, 0, stream>>>(tokens, emb, x, xb);

    for (int blk = 0; blk < NBB; blk++) {
        dim3 gEE64(EE / 128, M / 64);    // (4,128) = 512 wgs
        dim3 gQKV(3 * EE / 128, M / 128);// (12,64)
        dim3 gFF(FFF / 128, M / 128);    // (16,64)
        const size_t wE = (size_t)blk * EE * EE;

        gemm_bf16<<<gQKV, 256, 0, stream>>>(xb, WqkvT + blk * zQKV, beff + (size_t)blk * 1536, qb, M, 3 * EE, EE, GF_SCATTER3);

        vtrans_kernel<<<dim3(SS / 64, BB * HH), 256, 0, stream>>>(vb, vTb);

        attn_mfma<<<dim3(512), 512, 0, stream>>>(qb, kb, vTb, ao);

        gemm_bf16_m64<<<gEE64, 256, 0, stream>>>(ao, WoT + wE, nullptr, t0, M, EE, EE, 0);
        ln_kernel<<<M / 4, 256, 0, stream>>>(x, t0, ln1_g + blk * EE, ln1_b + blk * EE, xb);

        gemm_bf16<<<gFF, 256, 0, stream>>>(xb, fw1T + (size_t)blk * EE * FFF, f_b1 + blk * FFF, ffnb, M, FFF, EE, GF_RELU | GF_OUTBF16);
        gemm_bf16_m64<<<gEE64, 256, 0, stream>>>(ffnb, fw2T + (size_t)blk * EE * FFF, f_b2 + blk * EE, t0, M, EE, FFF, 0);
        ln_kernel<<<M / 4, 256, 0, stream>>>(x, t0, ln2_g + blk * EE, ln2_b + blk * EE, xb);
    }

    meanpart_kernel<<<dim3(64, BB), 256, 0, stream>>>(x, part);
    meancls_kernel<<<BB, 256, 0, stream>>>(part, cls_w, cls_b, (float*)d_out);
}

// Round 21
// 946.142 us; speedup vs baseline: 1.0861x; 1.0109x over previous
//
#include <hip/hip_runtime.h>
#include <hip/hip_bf16.h>
#include <math.h>

#define BB 4
#define SS 2048
#define EE 512
#define HH 8
#define DKK 64
#define LL 2
#define NBB 4
#define FFF 2048
#define CC 4
#define NBSE ((size_t)BB * SS * EE)

typedef __attribute__((ext_vector_type(8))) short bf16x8;
typedef __attribute__((ext_vector_type(4))) float f32x4;
using bf16 = __hip_bfloat16;

__device__ __forceinline__ float fast_exp2(float x) { return __builtin_amdgcn_exp2f(x); }

__device__ __forceinline__ void gload16(const bf16* g, bf16* l) {
    __builtin_amdgcn_global_load_lds((const __attribute__((address_space(1))) void*)g,
                                     (__attribute__((address_space(3))) void*)l, 16, 0, 0);
}
__device__ __forceinline__ unsigned short bf16bits(float f) {
    bf16 h = __float2bfloat16(f);
    return *(unsigned short*)&h;
}
__device__ __forceinline__ float bits2f(unsigned short u) {
    unsigned int x = ((unsigned int)u) << 16;
    return *(float*)&x;
}

// ---------------- embedding + positional encoding (f32 + bf16 copies) ----------------
__global__ __launch_bounds__(256) void embed_kernel(const int* __restrict__ tokens,
                                                    const float* __restrict__ emb,
                                                    float* __restrict__ x,
                                                    bf16* __restrict__ xb) {
    int i = blockIdx.x * blockDim.x + threadIdx.x;
    int total = BB * SS * EE / 2;
    if (i >= total) return;
    int pi  = i & (EE / 2 - 1);
    int row = i >> 8;
    int s   = row & (SS - 1);
    int tok = tokens[row];
    int e0  = pi * 2;
    const float kln = 9.210340371976184f / (float)EE;
    float arg = (float)s * expf(-(float)e0 * kln);
    float2 ev = *(const float2*)(emb + (size_t)tok * EE + e0);
    float2 o;
    o.x = ev.x + sinf(arg);
    o.y = ev.y + cosf(arg);
    *(float2*)(x + (size_t)row * EE + e0) = o;
    xb[(size_t)row * EE + e0]     = __float2bfloat16(o.x);
    xb[(size_t)row * EE + e0 + 1] = __float2bfloat16(o.y);
}

// ------- f32 [z][K][N] -> bf16 [z*zstride + (row_off+n)*K + k] transpose/cast -------
__global__ __launch_bounds__(256) void transpose_to_bf16(const float* __restrict__ in,
                                                         bf16* __restrict__ out,
                                                         int K, int N,
                                                         size_t zstride, int row_off) {
    const float* src = in + (size_t)blockIdx.z * K * N;
    bf16* dst = out + (size_t)blockIdx.z * zstride;
    int r0 = blockIdx.y * 64, c0 = blockIdx.x * 64;
    __shared__ float tl[64][65];
    int t = threadIdx.x;
    int lr = t >> 4, lc = (t & 15) * 4;
#pragma unroll
    for (int i = 0; i < 4; i++) {
        float4 v = *(const float4*)(src + (size_t)(r0 + lr + i * 16) * N + c0 + lc);
        tl[lr + i * 16][lc + 0] = v.x;
        tl[lr + i * 16][lc + 1] = v.y;
        tl[lr + i * 16][lc + 2] = v.z;
        tl[lr + i * 16][lc + 3] = v.w;
    }
    __syncthreads();
#pragma unroll
    for (int i = 0; i < 4; i++) {
        int n = lr + i * 16;
#pragma unroll
        for (int j = 0; j < 4; j++)
            dst[(size_t)(row_off + c0 + n) * K + r0 + lc + j] = __float2bfloat16(tl[lc + j][n]);
    }
}

// ---- fold quantum: W01 = W0 @ W1 (f32), beff = b0 @ W1 + b1 ----
__global__ __launch_bounds__(256) void fold_w01(const float* __restrict__ qw, const float* __restrict__ kw, const float* __restrict__ vw,
                                                const float* __restrict__ qbv, const float* __restrict__ kbv, const float* __restrict__ vbv,
                                                float* __restrict__ w01, float* __restrict__ beff) {
    int h = blockIdx.x, z = blockIdx.y, blk = blockIdx.z;
    const float* w  = z == 0 ? qw  : (z == 1 ? kw  : vw);
    const float* bi = z == 0 ? qbv : (z == 1 ? kbv : vbv);
    const float* W0 = w + ((size_t)(blk * LL + 0) * HH + h) * 4096;
    const float* W1 = w + ((size_t)(blk * LL + 1) * HH + h) * 4096;
    __shared__ float s0[64 * 64];
    __shared__ float s1[64 * 64];
    int t = threadIdx.x;
    for (int i = t; i < 4096; i += 256) { s0[i] = W0[i]; s1[i] = W1[i]; }
    __syncthreads();
    int d = t >> 2, e0 = (t & 3) * 16;
    float acc[16] = {};
    for (int c = 0; c < 64; c++) {
        float a = s0[d * 64 + c];
#pragma unroll
        for (int e = 0; e < 16; e++) acc[e] += a * s1[c * 64 + e0 + e];
    }
    float* wout = w01 + ((size_t)(blk * 3 + z) * HH + h) * 4096;
#pragma unroll
    for (int e = 0; e < 16; e++) wout[d * 64 + e0 + e] = acc[e];
    if (t < 64) {
        const float* b0 = bi + ((size_t)(blk * LL + 0) * HH + h) * 64;
        const float* b1 = bi + ((size_t)(blk * LL + 1) * HH + h) * 64;
        float a = b1[t];
        for (int c = 0; c < 64; c++) a += b0[c] * s1[c * 64 + t];
        beff[(size_t)blk * 1536 + z * 512 + h * 64 + t] = a;
    }
}

// ---- fold quantum into QKV weights ----
__global__ __launch_bounds__(256) void fold_wqkv(const float* __restrict__ Wq, const float* __restrict__ Wk, const float* __restrict__ Wv,
                                                 const float* __restrict__ w01, bf16* __restrict__ WqkvT) {
    int kc = blockIdx.x;
    int h  = blockIdx.y;
    int zb = blockIdx.z;
    int blk = zb / 3, z = zb % 3;
    const float* Wz  = (z == 0 ? Wq : (z == 1 ? Wk : Wv)) + (size_t)blk * EE * EE;
    const float* Wp  = w01 + ((size_t)zb * HH + h) * 4096;
    __shared__ float sw[64 * 64];
    __shared__ float sp[64 * 64];
    int t = threadIdx.x;
    for (int i = t; i < 4096; i += 256) {
        int kk = i >> 6, d = i & 63;
        sw[i] = Wz[(size_t)(kc * 64 + kk) * EE + h * 64 + d];
        sp[i] = Wp[i];
    }
    __syncthreads();
    int kk = t >> 2, dk0 = (t & 3) * 16;
    float acc[16] = {};
    for (int d = 0; d < 64; d++) {
        float a = sw[kk * 64 + d];
#pragma unroll
        for (int e = 0; e < 16; e++) acc[e] += a * sp[d * 64 + dk0 + e];
    }
    bf16* outb = WqkvT + (size_t)blk * 3 * EE * EE;
    int k = kc * 64 + kk;
#pragma unroll
    for (int e = 0; e < 16; e++)
        outb[(size_t)(z * 512 + h * 64 + dk0 + e) * EE + k] = __float2bfloat16(acc[e]);
}

// ---- v [bh][s][dk] -> vT [bh][dk][s] via LDS 64x64 tile ----
__global__ __launch_bounds__(256) void vtrans_kernel(const bf16* __restrict__ v, bf16* __restrict__ vT) {
    int s0 = blockIdx.x * 64, bh = blockIdx.y;
    __shared__ bf16 vt[64 * 72];
    int t = threadIdx.x;
    int r = t >> 2, c0 = (t & 3) * 16;
    const bf16* src = v + ((size_t)bh * SS + s0) * DKK;
    uint4 v0 = *(const uint4*)(src + (size_t)r * DKK + c0);
    uint4 v1 = *(const uint4*)(src + (size_t)r * DKK + c0 + 8);
    const unsigned short* e0 = (const unsigned short*)&v0;
    const unsigned short* e1 = (const unsigned short*)&v1;
#pragma unroll
    for (int j = 0; j < 8; j++) {
        ((unsigned short*)vt)[(c0 + j) * 72 + r]     = e0[j];
        ((unsigned short*)vt)[(c0 + 8 + j) * 72 + r] = e1[j];
    }
    __syncthreads();
    bf16* dst = vT + (size_t)bh * DKK * SS + s0;
    *(uint4*)(dst + (size_t)r * SS + c0)     = *(uint4*)&vt[r * 72 + c0];
    *(uint4*)(dst + (size_t)r * SS + c0 + 8) = *(uint4*)&vt[r * 72 + c0 + 8];
}

// ---------------- bf16 MFMA GEMM (128x128 tile): C[M,N] = A[M,K] @ BT[N,K]^T ----------------
#define GF_RELU 1
#define GF_SCATTER3 2
#define GF_OUTBF16 4
__global__ __launch_bounds__(256) void gemm_bf16(const bf16* __restrict__ A,
                                                 const bf16* __restrict__ BT,
                                                 const float* __restrict__ bias,
                                                 void* __restrict__ C,
                                                 int M, int N, int K, int flags) {
    __shared__ __align__(16) bf16 Asm[128 * 32];
    __shared__ __align__(16) bf16 Bsm[128 * 32];
    int t = threadIdx.x;
    int l = t & 63, w = t >> 6;
    int nbx = gridDim.x;
    int lin = blockIdx.y * nbx + blockIdx.x;
    int cpx = (nbx * gridDim.y) >> 3;
    int swz = (lin & 7) * cpx + (lin >> 3);
    int bm = (swz / nbx) * 128, bn = (swz % nbx) * 128;
    int wr = (w >> 1) * 64, wc = (w & 1) * 64;
    int lr = l & 15, lg = l >> 4;
    int ca = w * 2;
    int sr = l >> 2, sk = (l & 3) * 8;
    const bf16* ga  = A  + (size_t)(bm + ca * 16 + sr) * K + sk;
    const bf16* ga2 = ga + (size_t)16 * K;
    const bf16* gb  = BT + (size_t)(bn + ca * 16 + sr) * K + sk;
    const bf16* gb2 = gb + (size_t)16 * K;

    f32x4 acc[4][4];
#pragma unroll
    for (int m = 0; m < 4; m++)
#pragma unroll
        for (int n = 0; n < 4; n++) acc[m][n] = (f32x4){0.f, 0.f, 0.f, 0.f};

    for (int k0 = 0; k0 < K; k0 += 32) {
        __syncthreads();
        gload16(ga + k0,  &Asm[ca * 512]);
        gload16(ga2 + k0, &Asm[ca * 512 + 512]);
        gload16(gb + k0,  &Bsm[ca * 512]);
        gload16(gb2 + k0, &Bsm[ca * 512 + 512]);
        __syncthreads();
        bf16x8 af[4], bfr[4];
#pragma unroll
        for (int m = 0; m < 4; m++)
            af[m] = *(const bf16x8*)&Asm[(wr + m * 16 + lr) * 32 + lg * 8];
#pragma unroll
        for (int n = 0; n < 4; n++)
            bfr[n] = *(const bf16x8*)&Bsm[(wc + n * 16 + lr) * 32 + lg * 8];
#pragma unroll
        for (int m = 0; m < 4; m++)
#pragma unroll
            for (int n = 0; n < 4; n++)
                acc[m][n] = __builtin_amdgcn_mfma_f32_16x16x32_bf16(af[m], bfr[n], acc[m][n], 0, 0, 0);
    }

#pragma unroll
    for (int m = 0; m < 4; m++) {
        int row = bm + wr + m * 16 + lg * 4;
#pragma unroll
        for (int n = 0; n < 4; n++) {
            int col = bn + wc + n * 16 + lr;
            float bv = bias ? bias[col] : 0.f;
#pragma unroll
            for (int r = 0; r < 4; r++) {
                float v = acc[m][n][r] + bv;
                if (flags & GF_RELU) v = fmaxf(v, 0.f);
                int rr = row + r;
                if (flags & GF_SCATTER3) {
                    int tsel = col >> 9;
                    int b = rr >> 11, s = rr & (SS - 1);
                    int h = (col >> 6) & 7, dk = col & 63;
                    ((bf16*)C)[tsel * NBSE + (((size_t)(b * HH + h) * SS + s) << 6) + dk] = __float2bfloat16(v);
                } else if (flags & GF_OUTBF16) {
                    ((bf16*)C)[(size_t)rr * N + col] = __float2bfloat16(v);
                } else {
                    ((float*)C)[(size_t)rr * N + col] = v;
                }
            }
        }
    }
}

// ------- bf16 MFMA GEMM (64x128 tile, for N=512 shapes) -------
__global__ __launch_bounds__(256) void gemm_bf16_m64(const bf16* __restrict__ A,
                                                     const bf16* __restrict__ BT,
                                                     const float* __restrict__ bias,
                                                     void* __restrict__ C,
                                                     int M, int N, int K, int flags) {
    __shared__ __align__(16) bf16 Asm[64 * 32];
    __shared__ __align__(16) bf16 Bsm[128 * 32];
    int t = threadIdx.x;
    int l = t & 63, w = t >> 6;
    int nbx = gridDim.x;
    int lin = blockIdx.y * nbx + blockIdx.x;
    int cpx = (nbx * gridDim.y) >> 3;
    int swz = (lin & 7) * cpx + (lin >> 3);
    int bm = (swz / nbx) * 64, bn = (swz % nbx) * 128;
    int wr = (w >> 1) * 32, wc = (w & 1) * 64;
    int lr = l & 15, lg = l >> 4;
    int ca = w * 2;
    int sr = l >> 2, sk = (l & 3) * 8;
    const bf16* ga  = A  + (size_t)(bm + w * 16 + sr) * K + sk;
    const bf16* gb  = BT + (size_t)(bn + ca * 16 + sr) * K + sk;
    const bf16* gb2 = gb + (size_t)16 * K;

    f32x4 acc[2][4];
#pragma unroll
    for (int m = 0; m < 2; m++)
#pragma unroll
        for (int n = 0; n < 4; n++) acc[m][n] = (f32x4){0.f, 0.f, 0.f, 0.f};

    for (int k0 = 0; k0 < K; k0 += 32) {
        __syncthreads();
        gload16(ga + k0,  &Asm[w * 512]);
        gload16(gb + k0,  &Bsm[ca * 512]);
        gload16(gb2 + k0, &Bsm[ca * 512 + 512]);
        __syncthreads();
        bf16x8 af[2], bfr[4];
#pragma unroll
        for (int m = 0; m < 2; m++)
            af[m] = *(const bf16x8*)&Asm[(wr + m * 16 + lr) * 32 + lg * 8];
#pragma unroll
        for (int n = 0; n < 4; n++)
            bfr[n] = *(const bf16x8*)&Bsm[(wc + n * 16 + lr) * 32 + lg * 8];
#pragma unroll
        for (int m = 0; m < 2; m++)
#pragma unroll
            for (int n = 0; n < 4; n++)
                acc[m][n] = __builtin_amdgcn_mfma_f32_16x16x32_bf16(af[m], bfr[n], acc[m][n], 0, 0, 0);
    }

#pragma unroll
    for (int m = 0; m < 2; m++) {
        int row = bm + wr + m * 16 + lg * 4;
#pragma unroll
        for (int n = 0; n < 4; n++) {
            int col = bn + wc + n * 16 + lr;
            float bv = bias ? bias[col] : 0.f;
#pragma unroll
            for (int r = 0; r < 4; r++) {
                float v = acc[m][n][r] + bv;
                if (flags & GF_RELU) v = fmaxf(v, 0.f);
                int rr = row + r;
                if (flags & GF_OUTBF16) {
                    ((bf16*)C)[(size_t)rr * N + col] = __float2bfloat16(v);
                } else {
                    ((float*)C)[(size_t)rr * N + col] = v;
                }
            }
        }
    }
}

// ---- flash attention: 8 waves, 128 q/block, KVBLK=64, defer-max + deferred l-sum (R16) ----
__global__ __launch_bounds__(512) __attribute__((amdgpu_waves_per_eu(6, 6)))
void attn_mfma(const bf16* __restrict__ q,
               const bf16* __restrict__ k,
               const bf16* __restrict__ vT,
               bf16* __restrict__ ao) {
    __shared__ __align__(16) bf16 Ksm[64 * 72];
    __shared__ __align__(16) bf16 Vtm[64 * 72];
    __shared__ __align__(16) bf16 Psm[8 * 16 * 68];
    int wg  = blockIdx.x;
    int nw  = (wg & 7) * 64 + (wg >> 3);
    int bh  = nw >> 4;
    int q0  = (nw & 15) * 128;
    int b = bh >> 3, hh = bh & 7;
    int t = threadIdx.x, l = t & 63, w = t >> 6;
    int lr = l & 15, lg = l >> 4;
    bf16* Pw = &Psm[w * 16 * 68];

    bf16x8 qf[2];
#pragma unroll
    for (int ks = 0; ks < 2; ks++)
        qf[ks] = *(const bf16x8*)(q + ((size_t)bh * SS + q0 + w * 16 + lr) * DKK + ks * 32 + lg * 8);

    float m_run[4] = {-INFINITY, -INFINITY, -INFINITY, -INFINITY};
    float l_run[4] = {0.f, 0.f, 0.f, 0.f};
    f32x4 accO[4];
#pragma unroll
    for (int j = 0; j < 4; j++) accO[j] = (f32x4){0.f, 0.f, 0.f, 0.f};

    const bf16* kbase = k  + (size_t)bh * SS * DKK;
    const bf16* vbase = vT + (size_t)bh * DKK * SS;
    int srow = t >> 3, scol = (t & 7) * 8;

    uint4 kreg, vreg;
    kreg = *(const uint4*)(kbase + (size_t)srow * DKK + scol);
    vreg = *(const uint4*)(vbase + (size_t)srow * SS + scol);

    const float SC = 0.180336879f;

    for (int kt = 0; kt < SS; kt += 64) {
        __syncthreads();
        *(uint4*)&Ksm[srow * 72 + scol] = kreg;
        *(uint4*)&Vtm[srow * 72 + scol] = vreg;
        __syncthreads();
        if (kt + 64 < SS) {
            kreg = *(const uint4*)(kbase + (size_t)(kt + 64 + srow) * DKK + scol);
            vreg = *(const uint4*)(vbase + (size_t)srow * SS + kt + 64 + scol);
        }

        f32x4 s[4];
#pragma unroll
        for (int n = 0; n < 4; n++) s[n] = (f32x4){0.f, 0.f, 0.f, 0.f};
        __builtin_amdgcn_s_setprio(1);
#pragma unroll
        for (int n = 0; n < 4; n++)
#pragma unroll
            for (int ks = 0; ks < 2; ks++) {
                bf16x8 kf = *(const bf16x8*)&Ksm[(n * 16 + lr) * 72 + ks * 32 + lg * 8];
                s[n] = __builtin_amdgcn_mfma_f32_16x16x32_bf16(qf[ks], kf, s[n], 0, 0, 0);
            }
        __builtin_amdgcn_s_setprio(0);

#pragma unroll
        for (int n = 0; n < 4; n++) s[n] *= SC;
        float mx[4];
#pragma unroll
        for (int r = 0; r < 4; r++)
            mx[r] = fmaxf(fmaxf(s[0][r], s[1][r]), fmaxf(s[2][r], s[3][r]));
        bool ok = true;
#pragma unroll
        for (int r = 0; r < 4; r++) ok = ok && (mx[r] <= m_run[r] + 8.f);
        if (!__all(ok)) {
#pragma unroll
            for (int r = 0; r < 4; r++) {
                float t2 = mx[r];
                t2 = fmaxf(t2, __shfl_xor(t2, 1, 16));
                t2 = fmaxf(t2, __shfl_xor(t2, 2, 16));
                t2 = fmaxf(t2, __shfl_xor(t2, 4, 16));
                t2 = fmaxf(t2, __shfl_xor(t2, 8, 16));
                float mn = fmaxf(m_run[r], t2);
                float fc = fast_exp2(m_run[r] - mn);
                m_run[r] = mn;
                l_run[r] *= fc;
#pragma unroll
                for (int j = 0; j < 4; j++) accO[j][r] *= fc;
            }
        }
#pragma unroll
        for (int n = 0; n < 4; n++)
#pragma unroll
            for (int r = 0; r < 4; r++) {
                float p = fast_exp2(s[n][r] - m_run[r]);
                l_run[r] += p;
                s[n][r] = p;
            }

#pragma unroll
        for (int n = 0; n < 4; n++)
#pragma unroll
            for (int r = 0; r < 4; r++)
                Pw[(lg * 4 + r) * 68 + n * 16 + lr] = __float2bfloat16(s[n][r]);

        bf16x8 pa[2];
#pragma unroll
        for (int ks = 0; ks < 2; ks++)
            pa[ks] = *(const bf16x8*)&Pw[lr * 68 + ks * 32 + lg * 8];
        __builtin_amdgcn_s_setprio(1);
#pragma unroll
        for (int j = 0; j < 4; j++)
#pragma unroll
            for (int ks = 0; ks < 2; ks++) {
                bf16x8 vb8 = *(const bf16x8*)&Vtm[(j * 16 + lr) * 72 + ks * 32 + lg * 8];
                accO[j] = __builtin_amdgcn_mfma_f32_16x16x32_bf16(pa[ks], vb8, accO[j], 0, 0, 0);
            }
        __builtin_amdgcn_s_setprio(0);
    }

    float inv[4];
#pragma unroll
    for (int r = 0; r < 4; r++) {
        float ls = l_run[r];
        ls += __shfl_xor(ls, 1, 16);
        ls += __shfl_xor(ls, 2, 16);
        ls += __shfl_xor(ls, 4, 16);
        ls += __shfl_xor(ls, 8, 16);
        inv[r] = 1.f / ls;
    }
#pragma unroll
    for (int j = 0; j < 4; j++)
#pragma unroll
        for (int r = 0; r < 4; r++) {
            int row = q0 + w * 16 + lg * 4 + r;
            ao[((size_t)(b * SS) + row) * EE + hh * 64 + j * 16 + lr] = __float2bfloat16(accO[j][r] * inv[r]);
        }
}

// ------- layernorm(x + res_bf16): one WAVE per row, vector loads, shuffle-only reduction -------
__global__ __launch_bounds__(256) void ln_kernel(float* __restrict__ x,
                                                 const bf16* __restrict__ res,
                                                 const float* __restrict__ g,
                                                 const float* __restrict__ beta,
                                                 bf16* __restrict__ xb) {
    int t = threadIdx.x, lane = t & 63, wv = t >> 6;
    int row = blockIdx.x * 4 + wv;
    float* xr = x + (size_t)row * EE;
    const bf16* rr = res + (size_t)row * EE;
    int c0 = lane * 8;
    float4 a0 = *(const float4*)(xr + c0);
    float4 a1 = *(const float4*)(xr + c0 + 4);
    uint4 rv = *(const uint4*)(rr + c0);
    const unsigned short* re = (const unsigned short*)&rv;
    float v[8];
    v[0] = a0.x + bits2f(re[0]); v[1] = a0.y + bits2f(re[1]);
    v[2] = a0.z + bits2f(re[2]); v[3] = a0.w + bits2f(re[3]);
    v[4] = a1.x + bits2f(re[4]); v[5] = a1.y + bits2f(re[5]);
    v[6] = a1.z + bits2f(re[6]); v[7] = a1.w + bits2f(re[7]);
    float s = 0.f;
#pragma unroll
    for (int i = 0; i < 8; i++) s += v[i];
#pragma unroll
    for (int m = 1; m < 64; m <<= 1) s += __shfl_xor(s, m, 64);
    float mean = s * (1.f / EE);
    float qv = 0.f;
#pragma unroll
    for (int i = 0; i < 8; i++) { v[i] -= mean; qv += v[i] * v[i]; }
#pragma unroll
    for (int m = 1; m < 64; m <<= 1) qv += __shfl_xor(qv, m, 64);
    float rs = rsqrtf(qv * (1.f / EE) + 1e-5f);
    float4 gg0 = *(const float4*)(g + c0);
    float4 gg1 = *(const float4*)(g + c0 + 4);
    float4 bb0 = *(const float4*)(beta + c0);
    float4 bb1 = *(const float4*)(beta + c0 + 4);
    float o[8];
    o[0] = v[0] * rs * gg0.x + bb0.x; o[1] = v[1] * rs * gg0.y + bb0.y;
    o[2] = v[2] * rs * gg0.z + bb0.z; o[3] = v[3] * rs * gg0.w + bb0.w;
    o[4] = v[4] * rs * gg1.x + bb1.x; o[5] = v[5] * rs * gg1.y + bb1.y;
    o[6] = v[6] * rs * gg1.z + bb1.z; o[7] = v[7] * rs * gg1.w + bb1.w;
    *(float4*)(xr + c0)     = make_float4(o[0], o[1], o[2], o[3]);
    *(float4*)(xr + c0 + 4) = make_float4(o[4], o[5], o[6], o[7]);
    ushort4 pk0, pk1;
    pk0.x = bf16bits(o[0]); pk0.y = bf16bits(o[1]); pk0.z = bf16bits(o[2]); pk0.w = bf16bits(o[3]);
    pk1.x = bf16bits(o[4]); pk1.y = bf16bits(o[5]); pk1.z = bf16bits(o[6]); pk1.w = bf16bits(o[7]);
    bf16* xbr = xb + (size_t)row * EE + c0;
    *(ushort4*)xbr       = pk0;
    *(ushort4*)(xbr + 4) = pk1;
}

// ---------------- mean over S (two stage) + classifier ----------------
__global__ __launch_bounds__(256) void meanpart_kernel(const float* __restrict__ x,
                                                       float* __restrict__ part) {
    int b = blockIdx.y, c = blockIdx.x;
    int t = threadIdx.x;
    float2 acc = make_float2(0.f, 0.f);
    for (int s = c * 32; s < c * 32 + 32; s++) {
        float2 v = *(const float2*)(x + ((size_t)b * SS + s) * EE + t * 2);
        acc.x += v.x; acc.y += v.y;
    }
    *(float2*)(part + (size_t)(b * 64 + c) * EE + t * 2) = acc;
}

__global__ __launch_bounds__(256) void meancls_kernel(const float* __restrict__ part,
                                                      const float* __restrict__ cw,
                                                      const float* __restrict__ cb,
                                                      float* __restrict__ out) {
    int b = blockIdx.x;
    int t = threadIdx.x;
    __shared__ float xm[EE];
    float2 acc = make_float2(0.f, 0.f);
    for (int i = 0; i < 64; i++) {
        float2 v = *(const float2*)(part + (size_t)(b * 64 + i) * EE + t * 2);
        acc.x += v.x; acc.y += v.y;
    }
    xm[t * 2]     = acc.x * (1.f / SS);
    xm[t * 2 + 1] = acc.y * (1.f / SS);
    __syncthreads();
    if (t < CC) {
        float a = cb[t];
        for (int e = 0; e < EE; e++) a += xm[e] * cw[e * CC + t];
        out[b * CC + t] = a;
    }
}

extern "C" void kernel_launch(void* const* d_in, const int* in_sizes, int n_in,
                              void* d_out, int out_size, void* d_ws, size_t ws_size,
                              hipStream_t stream) {
    (void)in_sizes; (void)n_in; (void)out_size; (void)ws_size;
    const int*   tokens = (const int*)d_in[0];
    const float* emb    = (const float*)d_in[1];
    const float* Wq     = (const float*)d_in[2];
    const float* Wk     = (const float*)d_in[3];
    const float* Wv     = (const float*)d_in[4];
    const float* Wo     = (const float*)d_in[5];
    const float* qh_w   = (const float*)d_in[6];
    const float* qh_b   = (const float*)d_in[7];
    const float* kh_w   = (const float*)d_in[8];
    const float* kh_b   = (const float*)d_in[9];
    const float* vh_w   = (const float*)d_in[10];
    const float* vh_b   = (const float*)d_in[11];
    const float* ln1_g  = (const float*)d_in[12];
    const float* ln1_b  = (const float*)d_in[13];
    const float* ln2_g  = (const float*)d_in[14];
    const float* ln2_b  = (const float*)d_in[15];
    const float* f_w1   = (const float*)d_in[16];
    const float* f_b1   = (const float*)d_in[17];
    const float* f_w2   = (const float*)d_in[18];
    const float* f_b2   = (const float*)d_in[19];
    const float* cls_w  = (const float*)d_in[20];
    const float* cls_b  = (const float*)d_in[21];

    const size_t nBSF = (size_t)BB * SS * FFF;
    float* x    = (float*)d_ws;
    float* t0   = x + NBSE;
    bf16* t0b   = (bf16*)t0;                 // bf16 view of the branch buffer
    float* part = t0 + NBSE;
    bf16* xb    = (bf16*)(part + (size_t)BB * 64 * EE);
    bf16* qb    = xb + NBSE;
    bf16* kb    = qb + NBSE;
    bf16* vb    = kb + NBSE;
    bf16* vTb   = vb + NBSE;
    bf16* ao    = vTb + NBSE;
    bf16* ffnb  = ao + NBSE;
    bf16* WqkvT = ffnb + nBSF;
    bf16* WoT   = WqkvT + (size_t)NBB * 3 * EE * EE;
    bf16* fw1T  = WoT + (size_t)NBB * EE * EE;
    bf16* fw2T  = fw1T + (size_t)NBB * EE * FFF;
    float* w01  = (float*)(fw2T + (size_t)NBB * EE * FFF);
    float* beff = w01 + (size_t)NBB * 3 * HH * DKK * DKK;

    const int M = BB * SS;   // 8192
    const size_t zQKV = (size_t)3 * EE * EE;

    fold_w01<<<dim3(HH, 3, NBB), 256, 0, stream>>>(qh_w, kh_w, vh_w, qh_b, kh_b, vh_b, w01, beff);
    fold_wqkv<<<dim3(8, HH, 3 * NBB), 256, 0, stream>>>(Wq, Wk, Wv, w01, WqkvT);
    transpose_to_bf16<<<dim3(EE / 64, EE / 64, NBB), 256, 0, stream>>>(Wo, WoT, EE, EE, (size_t)EE * EE, 0);
    transpose_to_bf16<<<dim3(FFF / 64, EE / 64, NBB), 256, 0, stream>>>(f_w1, fw1T, EE, FFF, (size_t)EE * FFF, 0);
    transpose_to_bf16<<<dim3(EE / 64, FFF / 64, NBB), 256, 0, stream>>>(f_w2, fw2T, FFF, EE, (size_t)EE * FFF, 0);

    embed_kernel<<<(BB * SS * EE / 2 + 255) / 256, 256, 0, stream>>>(tokens, emb, x, xb);

    for (int blk = 0; blk < NBB; blk++) {
        dim3 gEE64(EE / 128, M / 64);    // (4,128) = 512 wgs
        dim3 gQKV(3 * EE / 128, M / 128);// (12,64)
        dim3 gFF(FFF / 128, M / 128);    // (16,64)
        const size_t wE = (size_t)blk * EE * EE;

        gemm_bf16<<<gQKV, 256, 0, stream>>>(xb, WqkvT + blk * zQKV, beff + (size_t)blk * 1536, qb, M, 3 * EE, EE, GF_SCATTER3);

        vtrans_kernel<<<dim3(SS / 64, BB * HH), 256, 0, stream>>>(vb, vTb);

        attn_mfma<<<dim3(512), 512, 0, stream>>>(qb, kb, vTb, ao);

        gemm_bf16_m64<<<gEE64, 256, 0, stream>>>(ao, WoT + wE, nullptr, t0b, M, EE, EE, GF_OUTBF16);
        ln_kernel<<<M / 4, 256, 0, stream>>>(x, t0b, ln1_g + blk * EE, ln1_b + blk * EE, xb);

        gemm_bf16<<<gFF, 256, 0, stream>>>(xb, fw1T + (size_t)blk * EE * FFF, f_b1 + blk * FFF, ffnb, M, FFF, EE, GF_RELU | GF_OUTBF16);
        gemm_bf16_m64<<<gEE64, 256, 0, stream>>>(ffnb, fw2T + (size_t)blk * EE * FFF, f_b2 + blk * EE, t0b, M, EE, FFF, GF_OUTBF16);
        ln_kernel<<<M / 4, 256, 0, stream>>>(x, t0b, ln2_g + blk * EE, ln2_b + blk * EE, xb);
    }

    meanpart_kernel<<<dim3(64, BB), 256, 0, stream>>>(x, part);
    meancls_kernel<<<BB, 256, 0, stream>>>(part, cls_w, cls_b, (float*)d_out);
}